// Round 10
// baseline (598.074 us; speedup 1.0000x reference)
//
#include <hip/hip_runtime.h>

// Problem constants (match reference)
#define NN   100000              // nodes
#define NE   1600000             // edges before self loops
#define ET   (NE + NN)           // edges incl. self loops
#define INF_ 128                 // input features
#define HID  64                  // hidden
#define NG   256                 // graphs
#define BN_EPS 1e-5f
#define NEG  0.2f

// hierarchical scan geometry
#define SCAN_T     256
#define SCAN_ELEM  8
#define SCAN_CHUNK (SCAN_T * SCAN_ELEM)
#define SCAN_NB    ((NN + SCAN_CHUNK - 1) / SCAN_CHUNK)  // 49 (<= 64, fits a wave)

// bucket partition geometry (CSR fill)
#define BSPAN_LOG 8
#define BSPAN     (1 << BSPAN_LOG)                 // 256 dst nodes per bucket
#define NBUK      ((NN + BSPAN - 1) / BSPAN)       // 391
#define P1_EPT    16
#define P1_CHUNK  (256 * P1_EPT)                   // 4096 edges per block

__device__ __forceinline__ float lrelu(float v) { return v > 0.f ? v : NEG * v; }

__device__ __forceinline__ float readlane_f(float v, int l) {
  return __int_as_float(__builtin_amdgcn_readlane(__float_as_int(v), l));
}

// ---------------- CSR build (edges sorted by dst) ----------------

__global__ __launch_bounds__(256) void hist_k(const int* __restrict__ ei,
                                              int* __restrict__ deg) {
  int i = blockIdx.x * 256 + threadIdx.x;
  if (i >= ET) return;
  int dst = i < NE ? ei[NE + i] : i - NE;
  atomicAdd(&deg[dst], 1);
}

__global__ __launch_bounds__(SCAN_T) void scan_bsums_k(const int* __restrict__ deg,
                                                       int* __restrict__ bsum) {
  __shared__ int red[SCAN_T];
  int b = blockIdx.x, t = threadIdx.x;
  int base = b * SCAN_CHUNK + t * SCAN_ELEM;
  int s = 0;
#pragma unroll
  for (int i = 0; i < SCAN_ELEM; ++i) {
    int idx = base + i;
    if (idx < NN) s += deg[idx];
  }
  red[t] = s;
  __syncthreads();
  for (int off = SCAN_T / 2; off; off >>= 1) {
    if (t < off) red[t] += red[t + off];
    __syncthreads();
  }
  if (t == 0) bsum[b] = red[0];
}

__global__ __launch_bounds__(64) void scan_bbase_k(const int* __restrict__ bsum,
                                                   int* __restrict__ bbase) {
  int t = threadIdx.x;
  int v = (t < SCAN_NB) ? bsum[t] : 0;
  int inc = v;
  for (int off = 1; off < 64; off <<= 1) {
    int n = __shfl_up(inc, off);
    if (t >= off) inc += n;
  }
  if (t < SCAN_NB) bbase[t] = inc - v;
}

__global__ __launch_bounds__(SCAN_T) void scan_final_k(
    const int* __restrict__ deg, const int* __restrict__ bbase,
    int* __restrict__ rowptr, int* __restrict__ cursor) {
  __shared__ int tsum[SCAN_T];
  int b = blockIdx.x, t = threadIdx.x;
  int base = b * SCAN_CHUNK + t * SCAN_ELEM;
  int loc[SCAN_ELEM];
  int s = 0;
#pragma unroll
  for (int i = 0; i < SCAN_ELEM; ++i) {
    int idx = base + i;
    int v = (idx < NN) ? deg[idx] : 0;
    loc[i] = s;
    s += v;
  }
  tsum[t] = s;
  __syncthreads();
  for (int off = 1; off < SCAN_T; off <<= 1) {
    int v = tsum[t];
    int add = (t >= off) ? tsum[t - off] : 0;
    __syncthreads();
    tsum[t] = v + add;
    __syncthreads();
  }
  int tbase = bbase[b] + (t ? tsum[t - 1] : 0);
#pragma unroll
  for (int i = 0; i < SCAN_ELEM; ++i) {
    int idx = base + i;
    if (idx < NN) {
      int r = tbase + loc[i];
      rowptr[idx] = r;
      cursor[idx] = r;
    }
  }
  if (b == gridDim.x - 1 && t == SCAN_T - 1) rowptr[NN] = bbase[b] + tsum[SCAN_T - 1];
}

// staging cursors (one per bucket, init = CSR offset of bucket start);
// also zero-inits fsum/fsq for the layer-1 aggregation (folded memsets).
__global__ __launch_bounds__(512) void bcur_init_k(const int* __restrict__ rowptr,
                                                   int* __restrict__ bcur,
                                                   float* __restrict__ fsum,
                                                   float* __restrict__ fsq) {
  int b = threadIdx.x + blockIdx.x * 512;
  if (b < NBUK) bcur[b] = rowptr[b << BSPAN_LOG];
  if (b < HID) { fsum[b] = 0.f; fsq[b] = 0.f; }
}

// phase 1: partition edges into dst-buckets. LDS histogram -> one global
// reservation per bucket per block -> contiguous staging runs (8B int2).
__global__ __launch_bounds__(256) void part1_k(const int* __restrict__ ei,
                                               int* __restrict__ bcur,
                                               int2* __restrict__ stage) {
  __shared__ int hist[NBUK];
  __shared__ int base[NBUK];
  int t = threadIdx.x;
  for (int b = t; b < NBUK; b += 256) hist[b] = 0;
  __syncthreads();
  int chunk = blockIdx.x * P1_CHUNK;
  int myb[P1_EPT], myr[P1_EPT], mys[P1_EPT], myd[P1_EPT];
#pragma unroll
  for (int it = 0; it < P1_EPT; ++it) {
    int i = chunk + it * 256 + t;
    bool v = i < ET;
    int src = 0, dst = 0;
    if (v) {
      src = i < NE ? ei[i] : i - NE;
      dst = i < NE ? ei[NE + i] : i - NE;
    }
    myb[it] = v ? (dst >> BSPAN_LOG) : -1;
    mys[it] = src;
    myd[it] = dst;
    myr[it] = v ? atomicAdd(&hist[dst >> BSPAN_LOG], 1) : 0;
  }
  __syncthreads();
  for (int b = t; b < NBUK; b += 256)
    base[b] = hist[b] ? atomicAdd(&bcur[b], hist[b]) : 0;
  __syncthreads();
#pragma unroll
  for (int it = 0; it < P1_EPT; ++it)
    if (myb[it] >= 0)
      stage[base[myb[it]] + myr[it]] = make_int2(mys[it], myd[it]);
}

// phase 2: one block per bucket -> the ~17KB esrc window stays on one XCD L2
__global__ __launch_bounds__(256) void part2_k(const int2* __restrict__ stage,
                                               const int* __restrict__ rowptr,
                                               int* __restrict__ cursor,
                                               int* __restrict__ esrc) {
  int b = blockIdx.x;
  int s = rowptr[b << BSPAN_LOG];
  int e = rowptr[min((b + 1) << BSPAN_LOG, NN)];
  for (int i = s + threadIdx.x; i < e; i += 256) {
    int2 p = stage[i];
    int pos = atomicAdd(&cursor[p.y], 1);
    esrc[pos] = p.x;
  }
}

// ---------------- GEMM + attention logits ----------------
// h = (x*scale+shift) @ W ; alpha_s = h.as ; alpha_d = h.ad
// BN affine folded into LDS copy: WlT = (W*scale)^T, cvec = shift@W.
// W TRANSPOSED in LDS, STRIDE = K+1 (odd => banks (f+k)%32, 2-way = free).
// 4 rows/wave; the wave's 4 x-rows loaded cooperatively then broadcast via
// v_readlane. NOTE R5: 8 rows/wave -> 256 VGPR -> occupancy collapse.
// NOTE R7: stride K+4 was an 8-way bank conflict (4.8M conflict cycles).
template <int K>
__global__ __launch_bounds__(256) void gemm_att(
    const float* __restrict__ x, const float* __restrict__ scale,
    const float* __restrict__ shift, const float* __restrict__ W,
    const float* __restrict__ a_s, const float* __restrict__ a_d,
    float* __restrict__ h, float* __restrict__ sv_out, float* __restrict__ dv_out) {
  constexpr int STRIDE = K + 1;
  constexpr int XPL = 4 * K / 64;          // floats per lane (K=128 -> 8)
  constexpr int NV4 = XPL / 4;             // float4 loads per lane
  __shared__ float WlT[HID * STRIDE];
  __shared__ float cvec[HID];
  int tid = threadIdx.x;
  if (tid < HID) cvec[tid] = 0.f;
  __syncthreads();
  if (scale != nullptr) {
    float clocal = 0.f;
    for (int i = tid; i < K * HID; i += 256) {
      int k = i >> 6, f = i & 63;            // HID == 64; k wave-uniform
      float w = W[i];                        // coalesced
      clocal += shift[k] * w;
      WlT[f * STRIDE + k] = w * scale[k];
    }
    atomicAdd(&cvec[tid & 63], clocal);      // feature index fixed per thread
  } else {
    for (int i = tid; i < K * HID; i += 256) {
      int k = i >> 6, f = i & 63;
      WlT[f * STRIDE + k] = W[i];
    }
  }
  __syncthreads();

  int lane = tid & 63;
  int wid = tid >> 6;
  int row0 = blockIdx.x * 16 + wid * 4;     // NN % 16 == 0, no tail
  float cv = cvec[lane];
  float acc[4] = {cv, cv, cv, cv};

  // cooperative x load: flat = lane*XPL + (v*4+j) over rows row0..row0+3
  float xr[XPL];
  const float* xbase = x + (size_t)row0 * K;
#pragma unroll
  for (int v = 0; v < NV4; ++v)
    *(float4*)&xr[v * 4] = *(const float4*)(xbase + lane * XPL + v * 4);

  const float* wrow = &WlT[lane * STRIDE];
#pragma unroll
  for (int g = 0; g < 16; ++g) {            // K/XPL == 16 for both K
    float wv[XPL];
#pragma unroll
    for (int v = 0; v < NV4; ++v)
      *(float4*)&wv[v * 4] = *(const float4*)(wrow + g * XPL + v * 4);
#pragma unroll
    for (int r = 0; r < 4; ++r) {
#pragma unroll
      for (int m = 0; m < XPL; ++m)
        acc[r] = fmaf(readlane_f(xr[m], r * 16 + g), wv[m], acc[r]);
    }
  }

  float asl = a_s[lane], adl = a_d[lane];
  float s0 = acc[0] * asl, d0 = acc[0] * adl;
  float s1 = acc[1] * asl, d1 = acc[1] * adl;
  float s2 = acc[2] * asl, d2 = acc[2] * adl;
  float s3 = acc[3] * asl, d3 = acc[3] * adl;
  h[(size_t)(row0 + 0) * HID + lane] = acc[0];
  h[(size_t)(row0 + 1) * HID + lane] = acc[1];
  h[(size_t)(row0 + 2) * HID + lane] = acc[2];
  h[(size_t)(row0 + 3) * HID + lane] = acc[3];
  for (int o = 32; o; o >>= 1) {
    s0 += __shfl_xor(s0, o); d0 += __shfl_xor(d0, o);
    s1 += __shfl_xor(s1, o); d1 += __shfl_xor(d1, o);
    s2 += __shfl_xor(s2, o); d2 += __shfl_xor(d2, o);
    s3 += __shfl_xor(s3, o); d3 += __shfl_xor(d3, o);
  }
  if (lane == 0) {
    sv_out[row0 + 0] = s0; dv_out[row0 + 0] = d0;
    sv_out[row0 + 1] = s1; dv_out[row0 + 1] = d1;
    sv_out[row0 + 2] = s2; dv_out[row0 + 2] = d2;
    sv_out[row0 + 3] = s3; dv_out[row0 + 3] = d3;
  }
}

// ---------------- fused per-dst GAT aggregation ----------------
// wave per node. Softmax phase: lane=edge (alpha=0 for lane>=deg).
// Gather phase: QUAD-EDGE float4 layout -- quad q = lane>>4 takes edge
// slot 4i+q; each lane loads float4 of features (4L..4L+3). One load
// instruction covers 4 edges; the 4-deep unroll puts 16 edges in flight
// (vs 8 in R9's dual-edge, 4 in R4's single-edge). Over-read slots
// (>= deg) have alpha==0 and hit the cached slot-0 row. Epilogue:
// shfl_xor(16)+shfl_xor(32) combine, quad 0 stores float4.
__global__ __launch_bounds__(256) void gat_agg_k(
    const int* __restrict__ rowptr, const int* __restrict__ esrc,
    const float* __restrict__ s, const float* __restrict__ d,
    const float* __restrict__ h, const float* __restrict__ bias,
    float* __restrict__ y, float* __restrict__ fsum, float* __restrict__ fsq) {
  __shared__ float lsum[HID], lsq[HID];
  int tid = threadIdx.x;
  if (tid < HID) { lsum[tid] = 0.f; lsq[tid] = 0.f; }
  __syncthreads();
  int lane = tid & 63;
  int quad = lane >> 4;
  int fl = (lane & 15) * 4;
  float4 bv = *(const float4*)&bias[fl];
  float4 ls = {0.f, 0.f, 0.f, 0.f}, lq = {0.f, 0.f, 0.f, 0.f};
  int wave = blockIdx.x * 4 + (tid >> 6);
  int nwaves = gridDim.x * 4;
  for (int node = wave; node < NN; node += nwaves) {
    int start = rowptr[node], end = rowptr[node + 1];
    int deg = end - start;
    float dn = d[node];
    float4 acc = {0.f, 0.f, 0.f, 0.f};
    if (deg <= 64) {
      int j = start + (lane < deg ? lane : 0);
      int sj = esrc[j];                         // coalesced
      float e = lrelu(s[sj] + dn);
      float ev = (lane < deg) ? e : -INFINITY;
      float m = ev;
      for (int o = 32; o; o >>= 1) m = fmaxf(m, __shfl_xor(m, o));
      float w = (lane < deg) ? __expf(e - m) : 0.f;
      float wsum = w;
      for (int o = 32; o; o >>= 1) wsum += __shfl_xor(wsum, o);
      float alpha = w / wsum;                   // 0 for slots >= deg
      for (int t = 0; t < deg; t += 16) {
#pragma unroll
        for (int i = 0; i < 4; ++i) {
          int e0 = t + 4 * i;
          int p0 = __builtin_amdgcn_readlane(sj, e0 + 0);
          int p1 = __builtin_amdgcn_readlane(sj, e0 + 1);
          int p2 = __builtin_amdgcn_readlane(sj, e0 + 2);
          int p3 = __builtin_amdgcn_readlane(sj, e0 + 3);
          float a0 = readlane_f(alpha, e0 + 0);
          float a1 = readlane_f(alpha, e0 + 1);
          float a2 = readlane_f(alpha, e0 + 2);
          float a3 = readlane_f(alpha, e0 + 3);
          int ps = quad < 2 ? (quad == 0 ? p0 : p1) : (quad == 2 ? p2 : p3);
          float aw = quad < 2 ? (quad == 0 ? a0 : a1) : (quad == 2 ? a2 : a3);
          float4 hv = *(const float4*)&h[(size_t)ps * HID + fl];
          acc.x = fmaf(aw, hv.x, acc.x);
          acc.y = fmaf(aw, hv.y, acc.y);
          acc.z = fmaf(aw, hv.z, acc.z);
          acc.w = fmaf(aw, hv.w, acc.w);
        }
      }
    } else {
      // generic chunked path (deg > 64): same quad-edge gather per chunk
      float m = -INFINITY;
      for (int j = start + lane; j < end; j += 64)
        m = fmaxf(m, lrelu(s[esrc[j]] + dn));
      for (int o = 32; o; o >>= 1) m = fmaxf(m, __shfl_xor(m, o));
      float wsum = 0.f;
      for (int j = start + lane; j < end; j += 64)
        wsum += __expf(lrelu(s[esrc[j]] + dn) - m);
      for (int o = 32; o; o >>= 1) wsum += __shfl_xor(wsum, o);
      float inv = 1.0f / wsum;
      for (int cb = start; cb < end; cb += 64) {
        int cc = min(64, end - cb);
        int j = cb + (lane < cc ? lane : 0);
        int sj = esrc[j];
        float alpha = (lane < cc) ? __expf(lrelu(s[sj] + dn) - m) * inv : 0.f;
        for (int t = 0; t < cc; t += 16) {
#pragma unroll
          for (int i = 0; i < 4; ++i) {
            int e0 = t + 4 * i;
            int p0 = __builtin_amdgcn_readlane(sj, e0 + 0);
            int p1 = __builtin_amdgcn_readlane(sj, e0 + 1);
            int p2 = __builtin_amdgcn_readlane(sj, e0 + 2);
            int p3 = __builtin_amdgcn_readlane(sj, e0 + 3);
            float a0 = readlane_f(alpha, e0 + 0);
            float a1 = readlane_f(alpha, e0 + 1);
            float a2 = readlane_f(alpha, e0 + 2);
            float a3 = readlane_f(alpha, e0 + 3);
            int ps = quad < 2 ? (quad == 0 ? p0 : p1) : (quad == 2 ? p2 : p3);
            float aw = quad < 2 ? (quad == 0 ? a0 : a1) : (quad == 2 ? a2 : a3);
            float4 hv = *(const float4*)&h[(size_t)ps * HID + fl];
            acc.x = fmaf(aw, hv.x, acc.x);
            acc.y = fmaf(aw, hv.y, acc.y);
            acc.z = fmaf(aw, hv.z, acc.z);
            acc.w = fmaf(aw, hv.w, acc.w);
          }
        }
      }
    }
    // cross-quad combine: every lane ends with the full per-feature sum
    acc.x += __shfl_xor(acc.x, 16); acc.x += __shfl_xor(acc.x, 32);
    acc.y += __shfl_xor(acc.y, 16); acc.y += __shfl_xor(acc.y, 32);
    acc.z += __shfl_xor(acc.z, 16); acc.z += __shfl_xor(acc.z, 32);
    acc.w += __shfl_xor(acc.w, 16); acc.w += __shfl_xor(acc.w, 32);
    if (quad == 0) {
      float vx = fmaxf(acc.x + bv.x, 0.f);
      float vy = fmaxf(acc.y + bv.y, 0.f);
      float vz = fmaxf(acc.z + bv.z, 0.f);
      float vw = fmaxf(acc.w + bv.w, 0.f);
      *(float4*)&y[(size_t)node * HID + fl] = make_float4(vx, vy, vz, vw);
      ls.x += vx; ls.y += vy; ls.z += vz; ls.w += vw;
      lq.x += vx * vx; lq.y += vy * vy; lq.z += vz * vz; lq.w += vw * vw;
    }
  }
  if (lane < 16) {
    atomicAdd(&lsum[fl + 0], ls.x);
    atomicAdd(&lsum[fl + 1], ls.y);
    atomicAdd(&lsum[fl + 2], ls.z);
    atomicAdd(&lsum[fl + 3], ls.w);
    atomicAdd(&lsq[fl + 0], lq.x);
    atomicAdd(&lsq[fl + 1], lq.y);
    atomicAdd(&lsq[fl + 2], lq.z);
    atomicAdd(&lsq[fl + 3], lq.w);
  }
  __syncthreads();
  if (tid < HID) { atomicAdd(&fsum[tid], lsum[tid]); atomicAdd(&fsq[tid], lsq[tid]); }
}

// computes BN affine; re-zeroes fsum/fsq for the next consumer; optionally
// zero-inits pooled/cnt for the pooling stage (folded memsets).
__global__ void bn_params(float* __restrict__ fsum, float* __restrict__ fsq,
                          const float* __restrict__ g, const float* __restrict__ b,
                          float* __restrict__ a_out, float* __restrict__ c_out,
                          float* __restrict__ pooled_z, float* __restrict__ cnt_z) {
  int f = threadIdx.x;
  float m = fsum[f] * (1.0f / NN);
  float v = fsq[f] * (1.0f / NN) - m * m;
  float a = g[f] * rsqrtf(v + BN_EPS);
  a_out[f] = a;
  c_out[f] = b[f] - m * a;
  fsum[f] = 0.f;
  fsq[f] = 0.f;
  if (pooled_z != nullptr) {
    for (int i = f; i < NG * HID; i += 64) pooled_z[i] = 0.f;
    for (int i = f; i < NG; i += 64) cnt_z[i] = 0.f;
  }
}

// segmented pool over sorted batch: wave per contiguous node range; register
// accumulate per graph run; one 64-lane atomic flush per run. Also counts.
__global__ __launch_bounds__(256) void pool_k(
    const float* __restrict__ y, const int* __restrict__ batch,
    float* __restrict__ pooled, float* __restrict__ cnt) {
  int wid = blockIdx.x * 4 + (threadIdx.x >> 6);
  int lane = threadIdx.x & 63;
  int nw = gridDim.x * 4;
  int per = (NN + nw - 1) / nw;
  int lo = wid * per, hi = min(lo + per, NN);
  if (lo >= hi) return;
  int g = batch[lo];
  float acc = 0.f, c = 0.f;
  for (int node = lo; node < hi; ++node) {
    int bg = batch[node];                 // wave-uniform
    if (bg != g) {
      atomicAdd(&pooled[g * HID + lane], acc);
      if (lane == 0) atomicAdd(&cnt[g], c);
      g = bg; acc = 0.f; c = 0.f;
    }
    acc += y[(size_t)node * HID + lane];
    c += 1.f;
  }
  atomicAdd(&pooled[g * HID + lane], acc);
  if (lane == 0) atomicAdd(&cnt[g], c);
}

// one block (64 threads) per graph: BN2 affine + mean + full MLP head
__global__ __launch_bounds__(64) void mlp_head(
    const float* __restrict__ pooled, const float* __restrict__ cnt,
    const float* __restrict__ aP, const float* __restrict__ cP,
    const float* __restrict__ m1w, const float* __restrict__ m1b,
    const float* __restrict__ m2w, const float* __restrict__ m2b,
    const float* __restrict__ m3w, const float* __restrict__ m3b,
    const float* __restrict__ m4w, const float* __restrict__ m4b,
    float* __restrict__ out) {
  __shared__ float p[64], z1[64], z2[16], z3[8];
  int g = blockIdx.x, f = threadIdx.x;
  float cv = fmaxf(cnt[g], 1.0f);
  p[f] = aP[f] * pooled[g * 64 + f] / cv + cP[f];
  __syncthreads();
  float a1 = m1b[f];
  for (int k = 0; k < 64; ++k) a1 += p[k] * m1w[k * 64 + f];
  z1[f] = fmaxf(a1, 0.f);
  __syncthreads();
  if (f < 16) {
    float a2 = m2b[f];
    for (int k = 0; k < 64; ++k) a2 += z1[k] * m2w[k * 16 + f];
    z2[f] = fmaxf(a2, 0.f);
  }
  __syncthreads();
  if (f < 8) {
    float a3 = m3b[f];
    for (int k = 0; k < 16; ++k) a3 += z2[k] * m3w[k * 8 + f];
    z3[f] = fmaxf(a3, 0.f);
  }
  __syncthreads();
  if (f < 10) {
    float a4 = m4b[f];
    for (int k = 0; k < 8; ++k) a4 += z3[k] * m4w[k * 10 + f];
    out[g * 10 + f] = a4;
  }
}

extern "C" void kernel_launch(void* const* d_in, const int* in_sizes, int n_in,
                              void* d_out, int out_size, void* d_ws, size_t ws_size,
                              hipStream_t stream) {
  const float* x   = (const float*)d_in[0];
  const int*   ei  = (const int*)d_in[1];
  const int*   bat = (const int*)d_in[2];
  const float* W1  = (const float*)d_in[3];
  const float* as1 = (const float*)d_in[4];
  const float* ad1 = (const float*)d_in[5];
  const float* b1  = (const float*)d_in[6];
  const float* W2  = (const float*)d_in[7];
  const float* as2 = (const float*)d_in[8];
  const float* ad2 = (const float*)d_in[9];
  const float* b2  = (const float*)d_in[10];
  const float* bng = (const float*)d_in[11];
  const float* bnb = (const float*)d_in[12];
  const float* m1w = (const float*)d_in[13];
  const float* m1b = (const float*)d_in[14];
  const float* m2w = (const float*)d_in[15];
  const float* m2b = (const float*)d_in[16];
  const float* m3w = (const float*)d_in[17];
  const float* m3b = (const float*)d_in[18];
  const float* m4w = (const float*)d_in[19];
  const float* m4b = (const float*)d_in[20];
  float* out = (float*)d_out;

  float* ws = (float*)d_ws;
  size_t off = 0;
  float* hbuf = ws + off; off += (size_t)NN * HID;   // GEMM output h (aliases stage)
  float* ybuf = ws + off; off += (size_t)NN * HID;   // layer output y
  float* sbuf = ws + off; off += NN;                 // alpha_s
  float* dbuf = ws + off; off += NN;                 // alpha_d
  int* deg    = (int*)(ws + off); off += NN;
  int* rowptr = (int*)(ws + off); off += NN + 1;
  int* cursor = (int*)(ws + off); off += NN;
  int* esrc   = (int*)(ws + off); off += ET;         // CSR: src per dst-sorted edge
  int* bsum   = (int*)(ws + off); off += SCAN_NB;
  int* bbase  = (int*)(ws + off); off += SCAN_NB;
  int* bcur   = (int*)(ws + off); off += NBUK;
  float* fsum = ws + off; off += HID;
  float* fsq  = ws + off; off += HID;
  float* aP   = ws + off; off += HID;                // BN scale
  float* cP   = ws + off; off += HID;                // BN shift
  float* pooled = ws + off; off += (size_t)NG * HID; // raw per-graph sums
  float* cnt  = ws + off; off += NG;
  int2* stage = (int2*)hbuf;  // 13.6MB staging aliases hbuf (free until gemm1)

  dim3 b256(256);
  const int gemmGrid = NN / 16;                      // 6250, exact
  const int edgeGrid = (ET + 255) / 256;
  const int p1Grid = (ET + P1_CHUNK - 1) / P1_CHUNK; // 416
  const int aggGrid = 2048;

  // ---------- CSR build (shared by both layers) ----------
  hipMemsetAsync(deg, 0, NN * 4, stream);
  hist_k<<<edgeGrid, b256, 0, stream>>>(ei, deg);
  scan_bsums_k<<<SCAN_NB, SCAN_T, 0, stream>>>(deg, bsum);
  scan_bbase_k<<<1, 64, 0, stream>>>(bsum, bbase);
  scan_final_k<<<SCAN_NB, SCAN_T, 0, stream>>>(deg, bbase, rowptr, cursor);
  bcur_init_k<<<1, 512, 0, stream>>>(rowptr, bcur, fsum, fsq);
  part1_k<<<p1Grid, b256, 0, stream>>>(ei, bcur, stage);
  part2_k<<<NBUK, b256, 0, stream>>>(stage, rowptr, cursor, esrc);

  // ---------- layer 1 ----------
  gemm_att<INF_><<<gemmGrid, b256, 0, stream>>>(x, nullptr, nullptr, W1, as1, ad1,
                                                hbuf, sbuf, dbuf);
  gat_agg_k<<<aggGrid, b256, 0, stream>>>(rowptr, esrc, sbuf, dbuf, hbuf, b1,
                                          ybuf, fsum, fsq);
  bn_params<<<1, 64, 0, stream>>>(fsum, fsq, bng, bnb, aP, cP, nullptr, nullptr);

  // ---------- layer 2 (BN affine folded into GEMM weight copy) ----------
  gemm_att<HID><<<gemmGrid, b256, 0, stream>>>(ybuf, aP, cP, W2, as2, ad2,
                                               hbuf, sbuf, dbuf);
  gat_agg_k<<<aggGrid, b256, 0, stream>>>(rowptr, esrc, sbuf, dbuf, hbuf, b2,
                                          ybuf, fsum, fsq);
  bn_params<<<1, 64, 0, stream>>>(fsum, fsq, bng, bnb, aP, cP, pooled, cnt);

  // ---------- pool (segmented, sorted batch) + MLP ----------
  pool_k<<<1024, b256, 0, stream>>>(ybuf, bat, pooled, cnt);
  mlp_head<<<NG, 64, 0, stream>>>(pooled, cnt, aP, cP, m1w, m1b, m2w, m2b,
                                  m3w, m3b, m4w, m4b, out);
}

// Round 11
// 527.098 us; speedup vs baseline: 1.1347x; 1.1347x over previous
//
#include <hip/hip_runtime.h>

// Problem constants (match reference)
#define NN   100000              // nodes
#define NE   1600000             // edges before self loops
#define ET   (NE + NN)           // edges incl. self loops
#define INF_ 128                 // input features
#define HID  64                  // hidden
#define NG   256                 // graphs
#define BN_EPS 1e-5f
#define NEG  0.2f

// hierarchical scan geometry
#define SCAN_T     256
#define SCAN_ELEM  8
#define SCAN_CHUNK (SCAN_T * SCAN_ELEM)
#define SCAN_NB    ((NN + SCAN_CHUNK - 1) / SCAN_CHUNK)  // 49 (<= 64, fits a wave)

// bucket partition geometry (CSR fill)
#define BSPAN_LOG 8
#define BSPAN     (1 << BSPAN_LOG)                 // 256 dst nodes per bucket
#define NBUK      ((NN + BSPAN - 1) / BSPAN)       // 391
#define P1_EPT    16
#define P1_CHUNK  (256 * P1_EPT)                   // 4096 edges per block

__device__ __forceinline__ float lrelu(float v) { return v > 0.f ? v : NEG * v; }

__device__ __forceinline__ float readlane_f(float v, int l) {
  return __int_as_float(__builtin_amdgcn_readlane(__float_as_int(v), l));
}

// ---------------- CSR build (edges sorted by dst) ----------------

__global__ __launch_bounds__(256) void hist_k(const int* __restrict__ ei,
                                              int* __restrict__ deg) {
  int i = blockIdx.x * 256 + threadIdx.x;
  if (i >= ET) return;
  int dst = i < NE ? ei[NE + i] : i - NE;
  atomicAdd(&deg[dst], 1);
}

__global__ __launch_bounds__(SCAN_T) void scan_bsums_k(const int* __restrict__ deg,
                                                       int* __restrict__ bsum) {
  __shared__ int red[SCAN_T];
  int b = blockIdx.x, t = threadIdx.x;
  int base = b * SCAN_CHUNK + t * SCAN_ELEM;
  int s = 0;
#pragma unroll
  for (int i = 0; i < SCAN_ELEM; ++i) {
    int idx = base + i;
    if (idx < NN) s += deg[idx];
  }
  red[t] = s;
  __syncthreads();
  for (int off = SCAN_T / 2; off; off >>= 1) {
    if (t < off) red[t] += red[t + off];
    __syncthreads();
  }
  if (t == 0) bsum[b] = red[0];
}

__global__ __launch_bounds__(64) void scan_bbase_k(const int* __restrict__ bsum,
                                                   int* __restrict__ bbase) {
  int t = threadIdx.x;
  int v = (t < SCAN_NB) ? bsum[t] : 0;
  int inc = v;
  for (int off = 1; off < 64; off <<= 1) {
    int n = __shfl_up(inc, off);
    if (t >= off) inc += n;
  }
  if (t < SCAN_NB) bbase[t] = inc - v;
}

__global__ __launch_bounds__(SCAN_T) void scan_final_k(
    const int* __restrict__ deg, const int* __restrict__ bbase,
    int* __restrict__ rowptr, int* __restrict__ cursor) {
  __shared__ int tsum[SCAN_T];
  int b = blockIdx.x, t = threadIdx.x;
  int base = b * SCAN_CHUNK + t * SCAN_ELEM;
  int loc[SCAN_ELEM];
  int s = 0;
#pragma unroll
  for (int i = 0; i < SCAN_ELEM; ++i) {
    int idx = base + i;
    int v = (idx < NN) ? deg[idx] : 0;
    loc[i] = s;
    s += v;
  }
  tsum[t] = s;
  __syncthreads();
  for (int off = 1; off < SCAN_T; off <<= 1) {
    int v = tsum[t];
    int add = (t >= off) ? tsum[t - off] : 0;
    __syncthreads();
    tsum[t] = v + add;
    __syncthreads();
  }
  int tbase = bbase[b] + (t ? tsum[t - 1] : 0);
#pragma unroll
  for (int i = 0; i < SCAN_ELEM; ++i) {
    int idx = base + i;
    if (idx < NN) {
      int r = tbase + loc[i];
      rowptr[idx] = r;
      cursor[idx] = r;
    }
  }
  if (b == gridDim.x - 1 && t == SCAN_T - 1) rowptr[NN] = bbase[b] + tsum[SCAN_T - 1];
}

// staging cursors (one per bucket, init = CSR offset of bucket start);
// also zero-inits fsum/fsq for the layer-1 aggregation (folded memsets).
__global__ __launch_bounds__(512) void bcur_init_k(const int* __restrict__ rowptr,
                                                   int* __restrict__ bcur,
                                                   float* __restrict__ fsum,
                                                   float* __restrict__ fsq) {
  int b = threadIdx.x + blockIdx.x * 512;
  if (b < NBUK) bcur[b] = rowptr[b << BSPAN_LOG];
  if (b < HID) { fsum[b] = 0.f; fsq[b] = 0.f; }
}

// phase 1: partition edges into dst-buckets. LDS histogram -> one global
// reservation per bucket per block -> contiguous staging runs (8B int2).
__global__ __launch_bounds__(256) void part1_k(const int* __restrict__ ei,
                                               int* __restrict__ bcur,
                                               int2* __restrict__ stage) {
  __shared__ int hist[NBUK];
  __shared__ int base[NBUK];
  int t = threadIdx.x;
  for (int b = t; b < NBUK; b += 256) hist[b] = 0;
  __syncthreads();
  int chunk = blockIdx.x * P1_CHUNK;
  int myb[P1_EPT], myr[P1_EPT], mys[P1_EPT], myd[P1_EPT];
#pragma unroll
  for (int it = 0; it < P1_EPT; ++it) {
    int i = chunk + it * 256 + t;
    bool v = i < ET;
    int src = 0, dst = 0;
    if (v) {
      src = i < NE ? ei[i] : i - NE;
      dst = i < NE ? ei[NE + i] : i - NE;
    }
    myb[it] = v ? (dst >> BSPAN_LOG) : -1;
    mys[it] = src;
    myd[it] = dst;
    myr[it] = v ? atomicAdd(&hist[dst >> BSPAN_LOG], 1) : 0;
  }
  __syncthreads();
  for (int b = t; b < NBUK; b += 256)
    base[b] = hist[b] ? atomicAdd(&bcur[b], hist[b]) : 0;
  __syncthreads();
#pragma unroll
  for (int it = 0; it < P1_EPT; ++it)
    if (myb[it] >= 0)
      stage[base[myb[it]] + myr[it]] = make_int2(mys[it], myd[it]);
}

// phase 2: one block per bucket -> the ~17KB esrc window stays on one XCD L2
__global__ __launch_bounds__(256) void part2_k(const int2* __restrict__ stage,
                                               const int* __restrict__ rowptr,
                                               int* __restrict__ cursor,
                                               int* __restrict__ esrc) {
  int b = blockIdx.x;
  int s = rowptr[b << BSPAN_LOG];
  int e = rowptr[min((b + 1) << BSPAN_LOG, NN)];
  for (int i = s + threadIdx.x; i < e; i += 256) {
    int2 p = stage[i];
    int pos = atomicAdd(&cursor[p.y], 1);
    esrc[pos] = p.x;
  }
}

// ---------------- GEMM + attention logits (v3) ----------------
// h = (x*scale+shift) @ W ; alpha_s = h.as ; alpha_d = h.ad
// BN affine folded into LDS weight copy; cvec = shift@W.
// Block = 16 rows. x tile staged in LDS via coalesced float4; inner loop
// reads x via WAVE-UNIFORM ds_read_b128 (same-address broadcast, no
// conflict) and W in original [k][f] layout (lane stride-1 ds_read_b32).
// No v_readlane in the loop (R8-R10 version: 512 readlane->fmac SGPR
// hazards per 4 rows made gemm ~125us). No global/scalar loads in loop.
// NOTE R5: 8 rows/wave -> 256 VGPR -> occupancy collapse. Keep 4 rows.
// NOTE R7: LDS stride K+4 for per-lane b128 was an 8-way bank conflict.
template <int K>
__global__ __launch_bounds__(256) void gemm_att(
    const float* __restrict__ x, const float* __restrict__ scale,
    const float* __restrict__ shift, const float* __restrict__ W,
    const float* __restrict__ a_s, const float* __restrict__ a_d,
    float* __restrict__ h, float* __restrict__ sv_out, float* __restrict__ dv_out) {
  constexpr int XPAD = K + 4;
  __shared__ float Wl[K * HID];          // [k][f]: lane reads stride-1
  __shared__ float xt[16 * XPAD];        // 16 staged x rows
  __shared__ float cvec[HID];
  int tid = threadIdx.x;
  if (tid < HID) cvec[tid] = 0.f;
  __syncthreads();
  if (scale != nullptr) {
    float clocal = 0.f;
    for (int i = tid; i < K * HID; i += 256) {
      int k = i >> 6;                      // HID == 64; k wave-uniform
      float w = W[i];                      // coalesced
      clocal += shift[k] * w;
      Wl[i] = w * scale[k];
    }
    atomicAdd(&cvec[tid & 63], clocal);    // feature index fixed per thread
  } else {
    for (int i = tid; i < K * HID; i += 256) Wl[i] = W[i];
  }
  // stage x tile (16 rows x K) with coalesced float4 loads
  {
    const float* xb = x + (size_t)blockIdx.x * 16 * K;
    for (int i = tid * 4; i < 16 * K; i += 256 * 4) {
      int r = i / K, k = i - r * K;        // K constexpr -> shifts
      *(float4*)&xt[r * XPAD + k] = *(const float4*)(xb + i);
    }
  }
  __syncthreads();

  int lane = tid & 63;
  int wid = tid >> 6;
  int row0 = blockIdx.x * 16 + wid * 4;    // NN % 16 == 0, no tail
  const float* x0 = &xt[(wid * 4 + 0) * XPAD];
  const float* x1 = &xt[(wid * 4 + 1) * XPAD];
  const float* x2 = &xt[(wid * 4 + 2) * XPAD];
  const float* x3 = &xt[(wid * 4 + 3) * XPAD];
  float cv = cvec[lane];
  float a0 = cv, a1 = cv, a2 = cv, a3 = cv;
#pragma unroll 4
  for (int k = 0; k < K; k += 4) {
    float4 v0 = *(const float4*)(x0 + k);  // uniform -> LDS broadcast
    float4 v1 = *(const float4*)(x1 + k);
    float4 v2 = *(const float4*)(x2 + k);
    float4 v3 = *(const float4*)(x3 + k);
    float w0 = Wl[(k + 0) * HID + lane];   // stride-1 across lanes
    float w1 = Wl[(k + 1) * HID + lane];
    float w2 = Wl[(k + 2) * HID + lane];
    float w3 = Wl[(k + 3) * HID + lane];
    a0 = fmaf(v0.x, w0, a0); a0 = fmaf(v0.y, w1, a0);
    a0 = fmaf(v0.z, w2, a0); a0 = fmaf(v0.w, w3, a0);
    a1 = fmaf(v1.x, w0, a1); a1 = fmaf(v1.y, w1, a1);
    a1 = fmaf(v1.z, w2, a1); a1 = fmaf(v1.w, w3, a1);
    a2 = fmaf(v2.x, w0, a2); a2 = fmaf(v2.y, w1, a2);
    a2 = fmaf(v2.z, w2, a2); a2 = fmaf(v2.w, w3, a2);
    a3 = fmaf(v3.x, w0, a3); a3 = fmaf(v3.y, w1, a3);
    a3 = fmaf(v3.z, w2, a3); a3 = fmaf(v3.w, w3, a3);
  }

  float asl = a_s[lane], adl = a_d[lane];
  h[(size_t)(row0 + 0) * HID + lane] = a0;
  h[(size_t)(row0 + 1) * HID + lane] = a1;
  h[(size_t)(row0 + 2) * HID + lane] = a2;
  h[(size_t)(row0 + 3) * HID + lane] = a3;
  float s0 = a0 * asl, d0 = a0 * adl;
  float s1 = a1 * asl, d1 = a1 * adl;
  float s2 = a2 * asl, d2 = a2 * adl;
  float s3 = a3 * asl, d3 = a3 * adl;
  for (int o = 32; o; o >>= 1) {
    s0 += __shfl_xor(s0, o); d0 += __shfl_xor(d0, o);
    s1 += __shfl_xor(s1, o); d1 += __shfl_xor(d1, o);
    s2 += __shfl_xor(s2, o); d2 += __shfl_xor(d2, o);
    s3 += __shfl_xor(s3, o); d3 += __shfl_xor(d3, o);
  }
  if (lane == 0) {
    sv_out[row0 + 0] = s0; dv_out[row0 + 0] = d0;
    sv_out[row0 + 1] = s1; dv_out[row0 + 1] = d1;
    sv_out[row0 + 2] = s2; dv_out[row0 + 2] = d2;
    sv_out[row0 + 3] = s3; dv_out[row0 + 3] = d3;
  }
}

// ---------------- fused per-dst GAT aggregation ----------------
// wave per node. Softmax phase: lane=edge (alpha=0 for lane>=deg).
// Gather phase: DUAL-EDGE float2 layout (R9 config, best measured:
// 123us, 28 VGPR, 62% occ; R10 quad-edge float4 regressed via VGPR 40 ->
// 44% occ). Lanes 0-31 take even-slot edges, 32-63 odd; float2/lane.
__global__ __launch_bounds__(256) void gat_agg_k(
    const int* __restrict__ rowptr, const int* __restrict__ esrc,
    const float* __restrict__ s, const float* __restrict__ d,
    const float* __restrict__ h, const float* __restrict__ bias,
    float* __restrict__ y, float* __restrict__ fsum, float* __restrict__ fsq) {
  __shared__ float lsum[HID], lsq[HID];
  int tid = threadIdx.x;
  if (tid < HID) { lsum[tid] = 0.f; lsq[tid] = 0.f; }
  __syncthreads();
  int lane = tid & 63;
  int half = lane >> 5;
  int fl = (lane & 31) * 2;
  float2 bv = *(const float2*)&bias[fl];
  float2 ls = {0.f, 0.f}, lq = {0.f, 0.f};
  int wave = blockIdx.x * 4 + (tid >> 6);
  int nwaves = gridDim.x * 4;
  for (int node = wave; node < NN; node += nwaves) {
    int start = rowptr[node], end = rowptr[node + 1];
    int deg = end - start;
    float dn = d[node];
    float2 acc = {0.f, 0.f};
    if (deg <= 64) {
      int j = start + (lane < deg ? lane : 0);
      int sj = esrc[j];                         // coalesced
      float e = lrelu(s[sj] + dn);
      float ev = (lane < deg) ? e : -INFINITY;
      float m = ev;
      for (int o = 32; o; o >>= 1) m = fmaxf(m, __shfl_xor(m, o));
      float w = (lane < deg) ? __expf(e - m) : 0.f;
      float wsum = w;
      for (int o = 32; o; o >>= 1) wsum += __shfl_xor(wsum, o);
      float alpha = w / wsum;                   // 0 for slots >= deg
      for (int t = 0; t < deg; t += 8) {
#pragma unroll
        for (int i = 0; i < 4; ++i) {
          int e0 = t + 2 * i;
          int p0 = __builtin_amdgcn_readlane(sj, e0);
          int p1 = __builtin_amdgcn_readlane(sj, e0 + 1);
          float a0 = readlane_f(alpha, e0);
          float a1 = readlane_f(alpha, e0 + 1);
          int ps = half ? p1 : p0;
          float aw = half ? a1 : a0;
          float2 hv = *(const float2*)&h[(size_t)ps * HID + fl];
          acc.x = fmaf(aw, hv.x, acc.x);
          acc.y = fmaf(aw, hv.y, acc.y);
        }
      }
    } else {
      // generic chunked path (deg > 64): same dual-edge gather per chunk
      float m = -INFINITY;
      for (int j = start + lane; j < end; j += 64)
        m = fmaxf(m, lrelu(s[esrc[j]] + dn));
      for (int o = 32; o; o >>= 1) m = fmaxf(m, __shfl_xor(m, o));
      float wsum = 0.f;
      for (int j = start + lane; j < end; j += 64)
        wsum += __expf(lrelu(s[esrc[j]] + dn) - m);
      for (int o = 32; o; o >>= 1) wsum += __shfl_xor(wsum, o);
      float inv = 1.0f / wsum;
      for (int cb = start; cb < end; cb += 64) {
        int cc = min(64, end - cb);
        int j = cb + (lane < cc ? lane : 0);
        int sj = esrc[j];
        float alpha = (lane < cc) ? __expf(lrelu(s[sj] + dn) - m) * inv : 0.f;
        for (int t = 0; t < cc; t += 8) {
#pragma unroll
          for (int i = 0; i < 4; ++i) {
            int e0 = t + 2 * i;
            int p0 = __builtin_amdgcn_readlane(sj, e0);
            int p1 = __builtin_amdgcn_readlane(sj, e0 + 1);
            float a0 = readlane_f(alpha, e0);
            float a1 = readlane_f(alpha, e0 + 1);
            int ps = half ? p1 : p0;
            float aw = half ? a1 : a0;
            float2 hv = *(const float2*)&h[(size_t)ps * HID + fl];
            acc.x = fmaf(aw, hv.x, acc.x);
            acc.y = fmaf(aw, hv.y, acc.y);
          }
        }
      }
    }
    // cross-half combine: both halves end with the full per-feature sum
    acc.x += __shfl_xor(acc.x, 32);
    acc.y += __shfl_xor(acc.y, 32);
    float vx = fmaxf(acc.x + bv.x, 0.f);
    float vy = fmaxf(acc.y + bv.y, 0.f);
    if (half == 0) {
      *(float2*)&y[(size_t)node * HID + fl] = make_float2(vx, vy);
      ls.x += vx; ls.y += vy;
      lq.x += vx * vx; lq.y += vy * vy;
    }
  }
  if (lane < 32) {
    atomicAdd(&lsum[fl + 0], ls.x);
    atomicAdd(&lsum[fl + 1], ls.y);
    atomicAdd(&lsq[fl + 0], lq.x);
    atomicAdd(&lsq[fl + 1], lq.y);
  }
  __syncthreads();
  if (tid < HID) { atomicAdd(&fsum[tid], lsum[tid]); atomicAdd(&fsq[tid], lsq[tid]); }
}

// computes BN affine; re-zeroes fsum/fsq for the next consumer; optionally
// zero-inits pooled/cnt for the pooling stage (folded memsets).
__global__ void bn_params(float* __restrict__ fsum, float* __restrict__ fsq,
                          const float* __restrict__ g, const float* __restrict__ b,
                          float* __restrict__ a_out, float* __restrict__ c_out,
                          float* __restrict__ pooled_z, float* __restrict__ cnt_z) {
  int f = threadIdx.x;
  float m = fsum[f] * (1.0f / NN);
  float v = fsq[f] * (1.0f / NN) - m * m;
  float a = g[f] * rsqrtf(v + BN_EPS);
  a_out[f] = a;
  c_out[f] = b[f] - m * a;
  fsum[f] = 0.f;
  fsq[f] = 0.f;
  if (pooled_z != nullptr) {
    for (int i = f; i < NG * HID; i += 64) pooled_z[i] = 0.f;
    for (int i = f; i < NG; i += 64) cnt_z[i] = 0.f;
  }
}

// segmented pool over sorted batch: wave per contiguous node range; register
// accumulate per graph run; one 64-lane atomic flush per run. Also counts.
__global__ __launch_bounds__(256) void pool_k(
    const float* __restrict__ y, const int* __restrict__ batch,
    float* __restrict__ pooled, float* __restrict__ cnt) {
  int wid = blockIdx.x * 4 + (threadIdx.x >> 6);
  int lane = threadIdx.x & 63;
  int nw = gridDim.x * 4;
  int per = (NN + nw - 1) / nw;
  int lo = wid * per, hi = min(lo + per, NN);
  if (lo >= hi) return;
  int g = batch[lo];
  float acc = 0.f, c = 0.f;
  for (int node = lo; node < hi; ++node) {
    int bg = batch[node];                 // wave-uniform
    if (bg != g) {
      atomicAdd(&pooled[g * HID + lane], acc);
      if (lane == 0) atomicAdd(&cnt[g], c);
      g = bg; acc = 0.f; c = 0.f;
    }
    acc += y[(size_t)node * HID + lane];
    c += 1.f;
  }
  atomicAdd(&pooled[g * HID + lane], acc);
  if (lane == 0) atomicAdd(&cnt[g], c);
}

// one block (64 threads) per graph: BN2 affine + mean + full MLP head
__global__ __launch_bounds__(64) void mlp_head(
    const float* __restrict__ pooled, const float* __restrict__ cnt,
    const float* __restrict__ aP, const float* __restrict__ cP,
    const float* __restrict__ m1w, const float* __restrict__ m1b,
    const float* __restrict__ m2w, const float* __restrict__ m2b,
    const float* __restrict__ m3w, const float* __restrict__ m3b,
    const float* __restrict__ m4w, const float* __restrict__ m4b,
    float* __restrict__ out) {
  __shared__ float p[64], z1[64], z2[16], z3[8];
  int g = blockIdx.x, f = threadIdx.x;
  float cv = fmaxf(cnt[g], 1.0f);
  p[f] = aP[f] * pooled[g * 64 + f] / cv + cP[f];
  __syncthreads();
  float a1 = m1b[f];
  for (int k = 0; k < 64; ++k) a1 += p[k] * m1w[k * 64 + f];
  z1[f] = fmaxf(a1, 0.f);
  __syncthreads();
  if (f < 16) {
    float a2 = m2b[f];
    for (int k = 0; k < 64; ++k) a2 += z1[k] * m2w[k * 16 + f];
    z2[f] = fmaxf(a2, 0.f);
  }
  __syncthreads();
  if (f < 8) {
    float a3 = m3b[f];
    for (int k = 0; k < 16; ++k) a3 += z2[k] * m3w[k * 8 + f];
    z3[f] = fmaxf(a3, 0.f);
  }
  __syncthreads();
  if (f < 10) {
    float a4 = m4b[f];
    for (int k = 0; k < 8; ++k) a4 += z3[k] * m4w[k * 10 + f];
    out[g * 10 + f] = a4;
  }
}

extern "C" void kernel_launch(void* const* d_in, const int* in_sizes, int n_in,
                              void* d_out, int out_size, void* d_ws, size_t ws_size,
                              hipStream_t stream) {
  const float* x   = (const float*)d_in[0];
  const int*   ei  = (const int*)d_in[1];
  const int*   bat = (const int*)d_in[2];
  const float* W1  = (const float*)d_in[3];
  const float* as1 = (const float*)d_in[4];
  const float* ad1 = (const float*)d_in[5];
  const float* b1  = (const float*)d_in[6];
  const float* W2  = (const float*)d_in[7];
  const float* as2 = (const float*)d_in[8];
  const float* ad2 = (const float*)d_in[9];
  const float* b2  = (const float*)d_in[10];
  const float* bng = (const float*)d_in[11];
  const float* bnb = (const float*)d_in[12];
  const float* m1w = (const float*)d_in[13];
  const float* m1b = (const float*)d_in[14];
  const float* m2w = (const float*)d_in[15];
  const float* m2b = (const float*)d_in[16];
  const float* m3w = (const float*)d_in[17];
  const float* m3b = (const float*)d_in[18];
  const float* m4w = (const float*)d_in[19];
  const float* m4b = (const float*)d_in[20];
  float* out = (float*)d_out;

  float* ws = (float*)d_ws;
  size_t off = 0;
  float* hbuf = ws + off; off += (size_t)NN * HID;   // GEMM output h (aliases stage)
  float* ybuf = ws + off; off += (size_t)NN * HID;   // layer output y
  float* sbuf = ws + off; off += NN;                 // alpha_s
  float* dbuf = ws + off; off += NN;                 // alpha_d
  int* deg    = (int*)(ws + off); off += NN;
  int* rowptr = (int*)(ws + off); off += NN + 1;
  int* cursor = (int*)(ws + off); off += NN;
  int* esrc   = (int*)(ws + off); off += ET;         // CSR: src per dst-sorted edge
  int* bsum   = (int*)(ws + off); off += SCAN_NB;
  int* bbase  = (int*)(ws + off); off += SCAN_NB;
  int* bcur   = (int*)(ws + off); off += NBUK;
  float* fsum = ws + off; off += HID;
  float* fsq  = ws + off; off += HID;
  float* aP   = ws + off; off += HID;                // BN scale
  float* cP   = ws + off; off += HID;                // BN shift
  float* pooled = ws + off; off += (size_t)NG * HID; // raw per-graph sums
  float* cnt  = ws + off; off += NG;
  int2* stage = (int2*)hbuf;  // 13.6MB staging aliases hbuf (free until gemm1)

  dim3 b256(256);
  const int gemmGrid = NN / 16;                      // 6250, exact
  const int edgeGrid = (ET + 255) / 256;
  const int p1Grid = (ET + P1_CHUNK - 1) / P1_CHUNK; // 416
  const int aggGrid = 2048;

  // ---------- CSR build (shared by both layers) ----------
  hipMemsetAsync(deg, 0, NN * 4, stream);
  hist_k<<<edgeGrid, b256, 0, stream>>>(ei, deg);
  scan_bsums_k<<<SCAN_NB, SCAN_T, 0, stream>>>(deg, bsum);
  scan_bbase_k<<<1, 64, 0, stream>>>(bsum, bbase);
  scan_final_k<<<SCAN_NB, SCAN_T, 0, stream>>>(deg, bbase, rowptr, cursor);
  bcur_init_k<<<1, 512, 0, stream>>>(rowptr, bcur, fsum, fsq);
  part1_k<<<p1Grid, b256, 0, stream>>>(ei, bcur, stage);
  part2_k<<<NBUK, b256, 0, stream>>>(stage, rowptr, cursor, esrc);

  // ---------- layer 1 ----------
  gemm_att<INF_><<<gemmGrid, b256, 0, stream>>>(x, nullptr, nullptr, W1, as1, ad1,
                                                hbuf, sbuf, dbuf);
  gat_agg_k<<<aggGrid, b256, 0, stream>>>(rowptr, esrc, sbuf, dbuf, hbuf, b1,
                                          ybuf, fsum, fsq);
  bn_params<<<1, 64, 0, stream>>>(fsum, fsq, bng, bnb, aP, cP, nullptr, nullptr);

  // ---------- layer 2 (BN affine folded into GEMM weight copy) ----------
  gemm_att<HID><<<gemmGrid, b256, 0, stream>>>(ybuf, aP, cP, W2, as2, ad2,
                                               hbuf, sbuf, dbuf);
  gat_agg_k<<<aggGrid, b256, 0, stream>>>(rowptr, esrc, sbuf, dbuf, hbuf, b2,
                                          ybuf, fsum, fsq);
  bn_params<<<1, 64, 0, stream>>>(fsum, fsq, bng, bnb, aP, cP, pooled, cnt);

  // ---------- pool (segmented, sorted batch) + MLP ----------
  pool_k<<<1024, b256, 0, stream>>>(ybuf, bat, pooled, cnt);
  mlp_head<<<NG, 64, 0, stream>>>(pooled, cnt, aP, cP, m1w, m1b, m2w, m2b,
                                  m3w, m3b, m4w, m4b, out);
}

// Round 12
// 497.359 us; speedup vs baseline: 1.2025x; 1.0598x over previous
//
#include <hip/hip_runtime.h>

// Problem constants (match reference)
#define NN   100000              // nodes
#define NE   1600000             // edges before self loops
#define ET   (NE + NN)           // edges incl. self loops
#define INF_ 128                 // input features
#define HID  64                  // hidden
#define NG   256                 // graphs
#define BN_EPS 1e-5f
#define NEG  0.2f

// hierarchical scan geometry
#define SCAN_T     256
#define SCAN_ELEM  8
#define SCAN_CHUNK (SCAN_T * SCAN_ELEM)
#define SCAN_NB    ((NN + SCAN_CHUNK - 1) / SCAN_CHUNK)  // 49 (<= 64, fits a wave)

// bucket partition geometry (CSR fill)
#define BSPAN_LOG 8
#define BSPAN     (1 << BSPAN_LOG)                 // 256 dst nodes per bucket
#define NBUK      ((NN + BSPAN - 1) / BSPAN)       // 391
#define P1_EPT    16
#define P1_CHUNK  (256 * P1_EPT)                   // 4096 edges per block

__device__ __forceinline__ float lrelu(float v) { return v > 0.f ? v : NEG * v; }

__device__ __forceinline__ float readlane_f(float v, int l) {
  return __int_as_float(__builtin_amdgcn_readlane(__float_as_int(v), l));
}

// ---------------- CSR build (edges sorted by dst) ----------------

__global__ __launch_bounds__(256) void hist_k(const int* __restrict__ ei,
                                              int* __restrict__ deg) {
  int i = blockIdx.x * 256 + threadIdx.x;
  if (i >= ET) return;
  int dst = i < NE ? ei[NE + i] : i - NE;
  atomicAdd(&deg[dst], 1);
}

__global__ __launch_bounds__(SCAN_T) void scan_bsums_k(const int* __restrict__ deg,
                                                       int* __restrict__ bsum) {
  __shared__ int red[SCAN_T];
  int b = blockIdx.x, t = threadIdx.x;
  int base = b * SCAN_CHUNK + t * SCAN_ELEM;
  int s = 0;
#pragma unroll
  for (int i = 0; i < SCAN_ELEM; ++i) {
    int idx = base + i;
    if (idx < NN) s += deg[idx];
  }
  red[t] = s;
  __syncthreads();
  for (int off = SCAN_T / 2; off; off >>= 1) {
    if (t < off) red[t] += red[t + off];
    __syncthreads();
  }
  if (t == 0) bsum[b] = red[0];
}

__global__ __launch_bounds__(64) void scan_bbase_k(const int* __restrict__ bsum,
                                                   int* __restrict__ bbase) {
  int t = threadIdx.x;
  int v = (t < SCAN_NB) ? bsum[t] : 0;
  int inc = v;
  for (int off = 1; off < 64; off <<= 1) {
    int n = __shfl_up(inc, off);
    if (t >= off) inc += n;
  }
  if (t < SCAN_NB) bbase[t] = inc - v;
}

__global__ __launch_bounds__(SCAN_T) void scan_final_k(
    const int* __restrict__ deg, const int* __restrict__ bbase,
    int* __restrict__ rowptr) {
  __shared__ int tsum[SCAN_T];
  int b = blockIdx.x, t = threadIdx.x;
  int base = b * SCAN_CHUNK + t * SCAN_ELEM;
  int loc[SCAN_ELEM];
  int s = 0;
#pragma unroll
  for (int i = 0; i < SCAN_ELEM; ++i) {
    int idx = base + i;
    int v = (idx < NN) ? deg[idx] : 0;
    loc[i] = s;
    s += v;
  }
  tsum[t] = s;
  __syncthreads();
  for (int off = 1; off < SCAN_T; off <<= 1) {
    int v = tsum[t];
    int add = (t >= off) ? tsum[t - off] : 0;
    __syncthreads();
    tsum[t] = v + add;
    __syncthreads();
  }
  int tbase = bbase[b] + (t ? tsum[t - 1] : 0);
#pragma unroll
  for (int i = 0; i < SCAN_ELEM; ++i) {
    int idx = base + i;
    if (idx < NN) rowptr[idx] = tbase + loc[i];
  }
  if (b == gridDim.x - 1 && t == SCAN_T - 1) rowptr[NN] = bbase[b] + tsum[SCAN_T - 1];
}

// staging cursors (one per bucket, init = CSR offset of bucket start);
// also zero-inits fsum/fsq for the layer-1 aggregation (folded memsets).
__global__ __launch_bounds__(512) void bcur_init_k(const int* __restrict__ rowptr,
                                                   int* __restrict__ bcur,
                                                   float* __restrict__ fsum,
                                                   float* __restrict__ fsq) {
  int b = threadIdx.x + blockIdx.x * 512;
  if (b < NBUK) bcur[b] = rowptr[b << BSPAN_LOG];
  if (b < HID) { fsum[b] = 0.f; fsq[b] = 0.f; }
}

// phase 1: partition edges into dst-buckets. LDS histogram -> one global
// reservation per bucket per block -> contiguous staging runs (8B int2).
__global__ __launch_bounds__(256) void part1_k(const int* __restrict__ ei,
                                               int* __restrict__ bcur,
                                               int2* __restrict__ stage) {
  __shared__ int hist[NBUK];
  __shared__ int base[NBUK];
  int t = threadIdx.x;
  for (int b = t; b < NBUK; b += 256) hist[b] = 0;
  __syncthreads();
  int chunk = blockIdx.x * P1_CHUNK;
  int myb[P1_EPT], myr[P1_EPT], mys[P1_EPT], myd[P1_EPT];
#pragma unroll
  for (int it = 0; it < P1_EPT; ++it) {
    int i = chunk + it * 256 + t;
    bool v = i < ET;
    int src = 0, dst = 0;
    if (v) {
      src = i < NE ? ei[i] : i - NE;
      dst = i < NE ? ei[NE + i] : i - NE;
    }
    myb[it] = v ? (dst >> BSPAN_LOG) : -1;
    mys[it] = src;
    myd[it] = dst;
    myr[it] = v ? atomicAdd(&hist[dst >> BSPAN_LOG], 1) : 0;
  }
  __syncthreads();
  for (int b = t; b < NBUK; b += 256)
    base[b] = hist[b] ? atomicAdd(&bcur[b], hist[b]) : 0;
  __syncthreads();
#pragma unroll
  for (int it = 0; it < P1_EPT; ++it)
    if (myb[it] >= 0)
      stage[base[myb[it]] + myr[it]] = make_int2(mys[it], myd[it]);
}

// phase 2: one block per bucket; per-dst cursors live in LDS (no global
// atomic round-trips). The ~17KB esrc window stays on one XCD L2.
__global__ __launch_bounds__(256) void part2_k(const int2* __restrict__ stage,
                                               const int* __restrict__ rowptr,
                                               int* __restrict__ esrc) {
  __shared__ int lcur[BSPAN];
  int b = blockIdx.x;
  int node0 = b << BSPAN_LOG;
  int t = threadIdx.x;
  if (node0 + t < NN) lcur[t] = rowptr[node0 + t];
  else lcur[t] = 0;
  __syncthreads();
  int s = rowptr[node0];
  int e = rowptr[min(node0 + BSPAN, NN)];
  for (int i = s + t; i < e; i += 256) {
    int2 p = stage[i];
    int pos = atomicAdd(&lcur[p.y - node0], 1);
    esrc[pos] = p.x;
  }
}

// ---------------- GEMM + attention logits (v4) ----------------
// h = (x*scale+shift) @ W ; alpha_s = h.as ; alpha_d = h.ad
// BN affine folded into LDS weight copy; cvec = shift@W.
// W in LDS [k][f] (lane stride-1 ds_read_b32, conflict-free). x rows are
// WAVE-UNIFORM: pointer forced through readfirstlane -> compiler emits
// s_load (scalar/constant cache) -> zero VALU/LDS cost for x; FMA takes
// the uniform operand from SGPR. Inner loop: 4 ds_read_b32 + 16 FMA per
// k-quad => FMA-bound.
// NOTE R5: 8 rows/wave -> 256 VGPR -> occupancy collapse. Keep 4 rows.
// NOTE R7: per-lane b128 at LDS stride K+4 was an 8-way bank conflict.
// NOTE R8-R10: x via VGPR+readlane = SGPR-hazard stalls (~125us); v3's
// LDS xt = LDS-throughput bound. Scalar-load x avoids both.
template <int K>
__global__ __launch_bounds__(256) void gemm_att(
    const float* __restrict__ x, const float* __restrict__ scale,
    const float* __restrict__ shift, const float* __restrict__ W,
    const float* __restrict__ a_s, const float* __restrict__ a_d,
    float* __restrict__ h, float* __restrict__ sv_out, float* __restrict__ dv_out) {
  __shared__ float Wl[K * HID];          // [k][f]: lane reads stride-1
  __shared__ float cvec[HID];
  int tid = threadIdx.x;
  if (tid < HID) cvec[tid] = 0.f;
  __syncthreads();
  if (scale != nullptr) {
    float clocal = 0.f;
    for (int i = tid; i < K * HID; i += 256) {
      int k = i >> 6;                      // HID == 64; k wave-uniform
      float w = W[i];                      // coalesced
      clocal += shift[k] * w;
      Wl[i] = w * scale[k];
    }
    atomicAdd(&cvec[tid & 63], clocal);    // feature index fixed per thread
  } else {
    for (int i = tid; i < K * HID; i += 256) Wl[i] = W[i];
  }
  __syncthreads();

  int lane = tid & 63;
  int wid = tid >> 6;
  int row0 = blockIdx.x * 16 + wid * 4;    // NN % 16 == 0, no tail
  int ur = __builtin_amdgcn_readfirstlane(row0);
  const float* xr0 = x + (size_t)ur * K;   // uniform -> scalar loads
  const float* xr1 = xr0 + K;
  const float* xr2 = xr0 + 2 * K;
  const float* xr3 = xr0 + 3 * K;
  float cv = cvec[lane];
  float a0 = cv, a1 = cv, a2 = cv, a3 = cv;
#pragma unroll 4
  for (int k = 0; k < K; k += 4) {
    float4 v0 = *(const float4*)(xr0 + k);
    float4 v1 = *(const float4*)(xr1 + k);
    float4 v2 = *(const float4*)(xr2 + k);
    float4 v3 = *(const float4*)(xr3 + k);
    float w0 = Wl[(k + 0) * HID + lane];   // stride-1 across lanes
    float w1 = Wl[(k + 1) * HID + lane];
    float w2 = Wl[(k + 2) * HID + lane];
    float w3 = Wl[(k + 3) * HID + lane];
    a0 = fmaf(v0.x, w0, a0); a0 = fmaf(v0.y, w1, a0);
    a0 = fmaf(v0.z, w2, a0); a0 = fmaf(v0.w, w3, a0);
    a1 = fmaf(v1.x, w0, a1); a1 = fmaf(v1.y, w1, a1);
    a1 = fmaf(v1.z, w2, a1); a1 = fmaf(v1.w, w3, a1);
    a2 = fmaf(v2.x, w0, a2); a2 = fmaf(v2.y, w1, a2);
    a2 = fmaf(v2.z, w2, a2); a2 = fmaf(v2.w, w3, a2);
    a3 = fmaf(v3.x, w0, a3); a3 = fmaf(v3.y, w1, a3);
    a3 = fmaf(v3.z, w2, a3); a3 = fmaf(v3.w, w3, a3);
  }

  float asl = a_s[lane], adl = a_d[lane];
  h[(size_t)(row0 + 0) * HID + lane] = a0;
  h[(size_t)(row0 + 1) * HID + lane] = a1;
  h[(size_t)(row0 + 2) * HID + lane] = a2;
  h[(size_t)(row0 + 3) * HID + lane] = a3;
  float s0 = a0 * asl, d0 = a0 * adl;
  float s1 = a1 * asl, d1 = a1 * adl;
  float s2 = a2 * asl, d2 = a2 * adl;
  float s3 = a3 * asl, d3 = a3 * adl;
  for (int o = 32; o; o >>= 1) {
    s0 += __shfl_xor(s0, o); d0 += __shfl_xor(d0, o);
    s1 += __shfl_xor(s1, o); d1 += __shfl_xor(d1, o);
    s2 += __shfl_xor(s2, o); d2 += __shfl_xor(d2, o);
    s3 += __shfl_xor(s3, o); d3 += __shfl_xor(d3, o);
  }
  if (lane == 0) {
    sv_out[row0 + 0] = s0; dv_out[row0 + 0] = d0;
    sv_out[row0 + 1] = s1; dv_out[row0 + 1] = d1;
    sv_out[row0 + 2] = s2; dv_out[row0 + 2] = d2;
    sv_out[row0 + 3] = s3; dv_out[row0 + 3] = d3;
  }
}

// ---------------- fused per-dst GAT aggregation ----------------
// wave per node. Softmax phase: lane=edge (alpha=0 for lane>=deg).
// Gather phase: DUAL-EDGE float2 layout (R9 config, best measured:
// 123us, 28 VGPR, 62% occ; R10 quad-edge float4 regressed via VGPR 40 ->
// 44% occ). Lanes 0-31 take even-slot edges, 32-63 odd; float2/lane.
// FETCH ~198MB = 8 XCD x 25.6MB h = compulsory-traffic floor for fp32 h.
__global__ __launch_bounds__(256) void gat_agg_k(
    const int* __restrict__ rowptr, const int* __restrict__ esrc,
    const float* __restrict__ s, const float* __restrict__ d,
    const float* __restrict__ h, const float* __restrict__ bias,
    float* __restrict__ y, float* __restrict__ fsum, float* __restrict__ fsq) {
  __shared__ float lsum[HID], lsq[HID];
  int tid = threadIdx.x;
  if (tid < HID) { lsum[tid] = 0.f; lsq[tid] = 0.f; }
  __syncthreads();
  int lane = tid & 63;
  int half = lane >> 5;
  int fl = (lane & 31) * 2;
  float2 bv = *(const float2*)&bias[fl];
  float2 ls = {0.f, 0.f}, lq = {0.f, 0.f};
  int wave = blockIdx.x * 4 + (tid >> 6);
  int nwaves = gridDim.x * 4;
  for (int node = wave; node < NN; node += nwaves) {
    int start = rowptr[node], end = rowptr[node + 1];
    int deg = end - start;
    float dn = d[node];
    float2 acc = {0.f, 0.f};
    if (deg <= 64) {
      int j = start + (lane < deg ? lane : 0);
      int sj = esrc[j];                         // coalesced
      float e = lrelu(s[sj] + dn);
      float ev = (lane < deg) ? e : -INFINITY;
      float m = ev;
      for (int o = 32; o; o >>= 1) m = fmaxf(m, __shfl_xor(m, o));
      float w = (lane < deg) ? __expf(e - m) : 0.f;
      float wsum = w;
      for (int o = 32; o; o >>= 1) wsum += __shfl_xor(wsum, o);
      float alpha = w / wsum;                   // 0 for slots >= deg
      for (int t = 0; t < deg; t += 8) {
#pragma unroll
        for (int i = 0; i < 4; ++i) {
          int e0 = t + 2 * i;
          int p0 = __builtin_amdgcn_readlane(sj, e0);
          int p1 = __builtin_amdgcn_readlane(sj, e0 + 1);
          float a0 = readlane_f(alpha, e0);
          float a1 = readlane_f(alpha, e0 + 1);
          int ps = half ? p1 : p0;
          float aw = half ? a1 : a0;
          float2 hv = *(const float2*)&h[(size_t)ps * HID + fl];
          acc.x = fmaf(aw, hv.x, acc.x);
          acc.y = fmaf(aw, hv.y, acc.y);
        }
      }
    } else {
      // generic chunked path (deg > 64): same dual-edge gather per chunk
      float m = -INFINITY;
      for (int j = start + lane; j < end; j += 64)
        m = fmaxf(m, lrelu(s[esrc[j]] + dn));
      for (int o = 32; o; o >>= 1) m = fmaxf(m, __shfl_xor(m, o));
      float wsum = 0.f;
      for (int j = start + lane; j < end; j += 64)
        wsum += __expf(lrelu(s[esrc[j]] + dn) - m);
      for (int o = 32; o; o >>= 1) wsum += __shfl_xor(wsum, o);
      float inv = 1.0f / wsum;
      for (int cb = start; cb < end; cb += 64) {
        int cc = min(64, end - cb);
        int j = cb + (lane < cc ? lane : 0);
        int sj = esrc[j];
        float alpha = (lane < cc) ? __expf(lrelu(s[sj] + dn) - m) * inv : 0.f;
        for (int t = 0; t < cc; t += 8) {
#pragma unroll
          for (int i = 0; i < 4; ++i) {
            int e0 = t + 2 * i;
            int p0 = __builtin_amdgcn_readlane(sj, e0);
            int p1 = __builtin_amdgcn_readlane(sj, e0 + 1);
            float a0 = readlane_f(alpha, e0);
            float a1 = readlane_f(alpha, e0 + 1);
            int ps = half ? p1 : p0;
            float aw = half ? a1 : a0;
            float2 hv = *(const float2*)&h[(size_t)ps * HID + fl];
            acc.x = fmaf(aw, hv.x, acc.x);
            acc.y = fmaf(aw, hv.y, acc.y);
          }
        }
      }
    }
    // cross-half combine: both halves end with the full per-feature sum
    acc.x += __shfl_xor(acc.x, 32);
    acc.y += __shfl_xor(acc.y, 32);
    float vx = fmaxf(acc.x + bv.x, 0.f);
    float vy = fmaxf(acc.y + bv.y, 0.f);
    if (half == 0) {
      *(float2*)&y[(size_t)node * HID + fl] = make_float2(vx, vy);
      ls.x += vx; ls.y += vy;
      lq.x += vx * vx; lq.y += vy * vy;
    }
  }
  if (lane < 32) {
    atomicAdd(&lsum[fl + 0], ls.x);
    atomicAdd(&lsum[fl + 1], ls.y);
    atomicAdd(&lsq[fl + 0], lq.x);
    atomicAdd(&lsq[fl + 1], lq.y);
  }
  __syncthreads();
  if (tid < HID) { atomicAdd(&fsum[tid], lsum[tid]); atomicAdd(&fsq[tid], lsq[tid]); }
}

// computes BN affine; re-zeroes fsum/fsq for the next consumer; optionally
// zero-inits pooled/cnt for the pooling stage (folded memsets).
__global__ void bn_params(float* __restrict__ fsum, float* __restrict__ fsq,
                          const float* __restrict__ g, const float* __restrict__ b,
                          float* __restrict__ a_out, float* __restrict__ c_out,
                          float* __restrict__ pooled_z, float* __restrict__ cnt_z) {
  int f = threadIdx.x;
  float m = fsum[f] * (1.0f / NN);
  float v = fsq[f] * (1.0f / NN) - m * m;
  float a = g[f] * rsqrtf(v + BN_EPS);
  a_out[f] = a;
  c_out[f] = b[f] - m * a;
  fsum[f] = 0.f;
  fsq[f] = 0.f;
  if (pooled_z != nullptr) {
    for (int i = f; i < NG * HID; i += 64) pooled_z[i] = 0.f;
    for (int i = f; i < NG; i += 64) cnt_z[i] = 0.f;
  }
}

// segmented pool over sorted batch: wave per contiguous node range; register
// accumulate per graph run; one 64-lane atomic flush per run. Also counts.
__global__ __launch_bounds__(256) void pool_k(
    const float* __restrict__ y, const int* __restrict__ batch,
    float* __restrict__ pooled, float* __restrict__ cnt) {
  int wid = blockIdx.x * 4 + (threadIdx.x >> 6);
  int lane = threadIdx.x & 63;
  int nw = gridDim.x * 4;
  int per = (NN + nw - 1) / nw;
  int lo = wid * per, hi = min(lo + per, NN);
  if (lo >= hi) return;
  int g = batch[lo];
  float acc = 0.f, c = 0.f;
  for (int node = lo; node < hi; ++node) {
    int bg = batch[node];                 // wave-uniform
    if (bg != g) {
      atomicAdd(&pooled[g * HID + lane], acc);
      if (lane == 0) atomicAdd(&cnt[g], c);
      g = bg; acc = 0.f; c = 0.f;
    }
    acc += y[(size_t)node * HID + lane];
    c += 1.f;
  }
  atomicAdd(&pooled[g * HID + lane], acc);
  if (lane == 0) atomicAdd(&cnt[g], c);
}

// one block (64 threads) per graph: BN2 affine + mean + full MLP head
__global__ __launch_bounds__(64) void mlp_head(
    const float* __restrict__ pooled, const float* __restrict__ cnt,
    const float* __restrict__ aP, const float* __restrict__ cP,
    const float* __restrict__ m1w, const float* __restrict__ m1b,
    const float* __restrict__ m2w, const float* __restrict__ m2b,
    const float* __restrict__ m3w, const float* __restrict__ m3b,
    const float* __restrict__ m4w, const float* __restrict__ m4b,
    float* __restrict__ out) {
  __shared__ float p[64], z1[64], z2[16], z3[8];
  int g = blockIdx.x, f = threadIdx.x;
  float cv = fmaxf(cnt[g], 1.0f);
  p[f] = aP[f] * pooled[g * 64 + f] / cv + cP[f];
  __syncthreads();
  float a1 = m1b[f];
  for (int k = 0; k < 64; ++k) a1 += p[k] * m1w[k * 64 + f];
  z1[f] = fmaxf(a1, 0.f);
  __syncthreads();
  if (f < 16) {
    float a2 = m2b[f];
    for (int k = 0; k < 64; ++k) a2 += z1[k] * m2w[k * 16 + f];
    z2[f] = fmaxf(a2, 0.f);
  }
  __syncthreads();
  if (f < 8) {
    float a3 = m3b[f];
    for (int k = 0; k < 16; ++k) a3 += z2[k] * m3w[k * 8 + f];
    z3[f] = fmaxf(a3, 0.f);
  }
  __syncthreads();
  if (f < 10) {
    float a4 = m4b[f];
    for (int k = 0; k < 8; ++k) a4 += z3[k] * m4w[k * 10 + f];
    out[g * 10 + f] = a4;
  }
}

extern "C" void kernel_launch(void* const* d_in, const int* in_sizes, int n_in,
                              void* d_out, int out_size, void* d_ws, size_t ws_size,
                              hipStream_t stream) {
  const float* x   = (const float*)d_in[0];
  const int*   ei  = (const int*)d_in[1];
  const int*   bat = (const int*)d_in[2];
  const float* W1  = (const float*)d_in[3];
  const float* as1 = (const float*)d_in[4];
  const float* ad1 = (const float*)d_in[5];
  const float* b1  = (const float*)d_in[6];
  const float* W2  = (const float*)d_in[7];
  const float* as2 = (const float*)d_in[8];
  const float* ad2 = (const float*)d_in[9];
  const float* b2  = (const float*)d_in[10];
  const float* bng = (const float*)d_in[11];
  const float* bnb = (const float*)d_in[12];
  const float* m1w = (const float*)d_in[13];
  const float* m1b = (const float*)d_in[14];
  const float* m2w = (const float*)d_in[15];
  const float* m2b = (const float*)d_in[16];
  const float* m3w = (const float*)d_in[17];
  const float* m3b = (const float*)d_in[18];
  const float* m4w = (const float*)d_in[19];
  const float* m4b = (const float*)d_in[20];
  float* out = (float*)d_out;

  float* ws = (float*)d_ws;
  size_t off = 0;
  float* hbuf = ws + off; off += (size_t)NN * HID;   // GEMM output h (aliases stage)
  float* ybuf = ws + off; off += (size_t)NN * HID;   // layer output y
  float* sbuf = ws + off; off += NN;                 // alpha_s
  float* dbuf = ws + off; off += NN;                 // alpha_d
  int* deg    = (int*)(ws + off); off += NN;
  int* rowptr = (int*)(ws + off); off += NN + 1;
  int* esrc   = (int*)(ws + off); off += ET;         // CSR: src per dst-sorted edge
  int* bsum   = (int*)(ws + off); off += SCAN_NB;
  int* bbase  = (int*)(ws + off); off += SCAN_NB;
  int* bcur   = (int*)(ws + off); off += NBUK;
  float* fsum = ws + off; off += HID;
  float* fsq  = ws + off; off += HID;
  float* aP   = ws + off; off += HID;                // BN scale
  float* cP   = ws + off; off += HID;                // BN shift
  float* pooled = ws + off; off += (size_t)NG * HID; // raw per-graph sums
  float* cnt  = ws + off; off += NG;
  int2* stage = (int2*)hbuf;  // 13.6MB staging aliases hbuf (free until gemm1)

  dim3 b256(256);
  const int gemmGrid = NN / 16;                      // 6250, exact
  const int edgeGrid = (ET + 255) / 256;
  const int p1Grid = (ET + P1_CHUNK - 1) / P1_CHUNK; // 416
  const int aggGrid = 2048;

  // ---------- CSR build (shared by both layers) ----------
  hipMemsetAsync(deg, 0, NN * 4, stream);
  hist_k<<<edgeGrid, b256, 0, stream>>>(ei, deg);
  scan_bsums_k<<<SCAN_NB, SCAN_T, 0, stream>>>(deg, bsum);
  scan_bbase_k<<<1, 64, 0, stream>>>(bsum, bbase);
  scan_final_k<<<SCAN_NB, SCAN_T, 0, stream>>>(deg, bbase, rowptr);
  bcur_init_k<<<1, 512, 0, stream>>>(rowptr, bcur, fsum, fsq);
  part1_k<<<p1Grid, b256, 0, stream>>>(ei, bcur, stage);
  part2_k<<<NBUK, b256, 0, stream>>>(stage, rowptr, esrc);

  // ---------- layer 1 ----------
  gemm_att<INF_><<<gemmGrid, b256, 0, stream>>>(x, nullptr, nullptr, W1, as1, ad1,
                                                hbuf, sbuf, dbuf);
  gat_agg_k<<<aggGrid, b256, 0, stream>>>(rowptr, esrc, sbuf, dbuf, hbuf, b1,
                                          ybuf, fsum, fsq);
  bn_params<<<1, 64, 0, stream>>>(fsum, fsq, bng, bnb, aP, cP, nullptr, nullptr);

  // ---------- layer 2 (BN affine folded into GEMM weight copy) ----------
  gemm_att<HID><<<gemmGrid, b256, 0, stream>>>(ybuf, aP, cP, W2, as2, ad2,
                                               hbuf, sbuf, dbuf);
  gat_agg_k<<<aggGrid, b256, 0, stream>>>(rowptr, esrc, sbuf, dbuf, hbuf, b2,
                                          ybuf, fsum, fsq);
  bn_params<<<1, 64, 0, stream>>>(fsum, fsq, bng, bnb, aP, cP, pooled, cnt);

  // ---------- pool (segmented, sorted batch) + MLP ----------
  pool_k<<<1024, b256, 0, stream>>>(ybuf, bat, pooled, cnt);
  mlp_head<<<NG, 64, 0, stream>>>(pooled, cnt, aP, cP, m1w, m1b, m2w, m2b,
                                  m3w, m3b, m4w, m4b, out);
}

// Round 13
// 474.478 us; speedup vs baseline: 1.2605x; 1.0482x over previous
//
#include <hip/hip_runtime.h>

// Problem constants (match reference)
#define NN   100000              // nodes
#define NE   1600000             // edges before self loops
#define ET   (NE + NN)           // edges incl. self loops
#define INF_ 128                 // input features
#define HID  64                  // hidden
#define NG   256                 // graphs
#define BN_EPS 1e-5f
#define NEG  0.2f

// hierarchical scan geometry
#define SCAN_T     256
#define SCAN_ELEM  8
#define SCAN_CHUNK (SCAN_T * SCAN_ELEM)
#define SCAN_NB    ((NN + SCAN_CHUNK - 1) / SCAN_CHUNK)  // 49 (<= 64, fits a wave)

// bucket partition geometry (CSR fill)
#define BSPAN_LOG 8
#define BSPAN     (1 << BSPAN_LOG)                 // 256 dst nodes per bucket
#define NBUK      ((NN + BSPAN - 1) / BSPAN)       // 391
#define BUKCAP    5120                             // >= mu+12sigma of bucket load
#define P1_EPT    16
#define P1_CHUNK  (256 * P1_EPT)                   // 4096 edges per block

__device__ __forceinline__ float lrelu(float v) { return v > 0.f ? v : NEG * v; }

__device__ __forceinline__ float readlane_f(float v, int l) {
  return __int_as_float(__builtin_amdgcn_readlane(__float_as_int(v), l));
}

// ---------------- unified init (replaces memsets + bcur_init) ----------------
__global__ __launch_bounds__(256) void init_k(
    int* __restrict__ deg, int* __restrict__ bukcur,
    float* __restrict__ fsum1, float* __restrict__ fsq1,
    float* __restrict__ fsum2, float* __restrict__ fsq2,
    float* __restrict__ pooled, float* __restrict__ cnt) {
  int i = blockIdx.x * 256 + threadIdx.x;
  if (i < NN) deg[i] = 0;
  if (i < NBUK) bukcur[i] = i * BUKCAP;
  if (i < HID) { fsum1[i] = 0.f; fsq1[i] = 0.f; fsum2[i] = 0.f; fsq2[i] = 0.f; }
  if (i < NG * HID) pooled[i] = 0.f;
  if (i < NG) cnt[i] = 0.f;
}

// ---------------- CSR build (edges sorted by dst) ----------------
// phase 1: partition edges into fixed-capacity dst-buckets (base b*BUKCAP,
// no rowptr dependency) AND build the per-dst degree histogram in the same
// pass (hist_k deleted). LDS histogram -> one global reservation per bucket
// per block -> contiguous staging runs (8B int2).
__global__ __launch_bounds__(256) void part1_k(const int* __restrict__ ei,
                                               int* __restrict__ deg,
                                               int* __restrict__ bukcur,
                                               int2* __restrict__ stage) {
  __shared__ int hist[NBUK];
  __shared__ int base[NBUK];
  int t = threadIdx.x;
  for (int b = t; b < NBUK; b += 256) hist[b] = 0;
  __syncthreads();
  int chunk = blockIdx.x * P1_CHUNK;
  int myb[P1_EPT], myr[P1_EPT], mys[P1_EPT], myd[P1_EPT];
#pragma unroll
  for (int it = 0; it < P1_EPT; ++it) {
    int i = chunk + it * 256 + t;
    bool v = i < ET;
    int src = 0, dst = 0;
    if (v) {
      src = i < NE ? ei[i] : i - NE;
      dst = i < NE ? ei[NE + i] : i - NE;
      atomicAdd(&deg[dst], 1);
    }
    myb[it] = v ? (dst >> BSPAN_LOG) : -1;
    mys[it] = src;
    myd[it] = dst;
    myr[it] = v ? atomicAdd(&hist[dst >> BSPAN_LOG], 1) : 0;
  }
  __syncthreads();
  for (int b = t; b < NBUK; b += 256)
    base[b] = hist[b] ? atomicAdd(&bukcur[b], hist[b]) : 0;
  __syncthreads();
#pragma unroll
  for (int it = 0; it < P1_EPT; ++it)
    if (myb[it] >= 0)
      stage[base[myb[it]] + myr[it]] = make_int2(mys[it], myd[it]);
}

__global__ __launch_bounds__(SCAN_T) void scan_bsums_k(const int* __restrict__ deg,
                                                       int* __restrict__ bsum) {
  __shared__ int red[SCAN_T];
  int b = blockIdx.x, t = threadIdx.x;
  int base = b * SCAN_CHUNK + t * SCAN_ELEM;
  int s = 0;
#pragma unroll
  for (int i = 0; i < SCAN_ELEM; ++i) {
    int idx = base + i;
    if (idx < NN) s += deg[idx];
  }
  red[t] = s;
  __syncthreads();
  for (int off = SCAN_T / 2; off; off >>= 1) {
    if (t < off) red[t] += red[t + off];
    __syncthreads();
  }
  if (t == 0) bsum[b] = red[0];
}

__global__ __launch_bounds__(64) void scan_bbase_k(const int* __restrict__ bsum,
                                                   int* __restrict__ bbase) {
  int t = threadIdx.x;
  int v = (t < SCAN_NB) ? bsum[t] : 0;
  int inc = v;
  for (int off = 1; off < 64; off <<= 1) {
    int n = __shfl_up(inc, off);
    if (t >= off) inc += n;
  }
  if (t < SCAN_NB) bbase[t] = inc - v;
}

__global__ __launch_bounds__(SCAN_T) void scan_final_k(
    const int* __restrict__ deg, const int* __restrict__ bbase,
    int* __restrict__ rowptr) {
  __shared__ int tsum[SCAN_T];
  int b = blockIdx.x, t = threadIdx.x;
  int base = b * SCAN_CHUNK + t * SCAN_ELEM;
  int loc[SCAN_ELEM];
  int s = 0;
#pragma unroll
  for (int i = 0; i < SCAN_ELEM; ++i) {
    int idx = base + i;
    int v = (idx < NN) ? deg[idx] : 0;
    loc[i] = s;
    s += v;
  }
  tsum[t] = s;
  __syncthreads();
  for (int off = 1; off < SCAN_T; off <<= 1) {
    int v = tsum[t];
    int add = (t >= off) ? tsum[t - off] : 0;
    __syncthreads();
    tsum[t] = v + add;
    __syncthreads();
  }
  int tbase = bbase[b] + (t ? tsum[t - 1] : 0);
#pragma unroll
  for (int i = 0; i < SCAN_ELEM; ++i) {
    int idx = base + i;
    if (idx < NN) rowptr[idx] = tbase + loc[i];
  }
  if (b == gridDim.x - 1 && t == SCAN_T - 1) rowptr[NN] = bbase[b] + tsum[SCAN_T - 1];
}

// phase 2: one block per bucket; per-dst cursors live in LDS (no global
// atomic round-trips). Bucket extent = [b*BUKCAP, bukcur[b]).
__global__ __launch_bounds__(256) void part2_k(const int2* __restrict__ stage,
                                               const int* __restrict__ bukcur,
                                               const int* __restrict__ rowptr,
                                               int* __restrict__ esrc) {
  __shared__ int lcur[BSPAN];
  int b = blockIdx.x;
  int node0 = b << BSPAN_LOG;
  int t = threadIdx.x;
  lcur[t] = (node0 + t < NN) ? rowptr[node0 + t] : 0;
  __syncthreads();
  int s = b * BUKCAP;
  int e = bukcur[b];
  for (int i = s + t; i < e; i += 256) {
    int2 p = stage[i];
    int pos = atomicAdd(&lcur[p.y - node0], 1);
    esrc[pos] = p.x;
  }
}

// ---------------- GEMM + attention logits (v4) ----------------
// h = (x*bnA+bnC) @ W ; alpha_s = h.as ; alpha_d = h.ad
// STATS=true: computes the BN affine (bnA,bnC) from fsum/fsq/g/b inline
// per block (replaces the bn_params kernel) and folds it into the LDS
// weight copy; cvec = bnC@W. W in LDS [k][f] (lane stride-1 ds_read_b32,
// conflict-free). x rows are WAVE-UNIFORM: pointer forced through
// readfirstlane -> scalar loads; FMA takes the uniform operand from SGPR.
// NOTE R5: 8 rows/wave -> 256 VGPR -> occupancy collapse. Keep 4 rows.
// NOTE R7: per-lane b128 at LDS stride K+4 was an 8-way bank conflict.
// NOTE R8-R10: x via VGPR+readlane = SGPR-hazard stalls (~125us); v3's
// LDS xt = LDS-throughput bound. Scalar-load x avoids both.
template <int K, bool STATS>
__global__ __launch_bounds__(256) void gemm_att(
    const float* __restrict__ x,
    const float* __restrict__ fsum, const float* __restrict__ fsq,
    const float* __restrict__ bng, const float* __restrict__ bnb,
    const float* __restrict__ W,
    const float* __restrict__ a_s, const float* __restrict__ a_d,
    float* __restrict__ h, float* __restrict__ sv_out, float* __restrict__ dv_out) {
  __shared__ float Wl[K * HID];          // [k][f]: lane reads stride-1
  __shared__ float cvec[HID];
  __shared__ float scl[HID], shf[HID];   // only used when STATS (K==HID)
  int tid = threadIdx.x;
  if (tid < HID) {
    cvec[tid] = 0.f;
    if (STATS) {
      float m = fsum[tid] * (1.0f / NN);
      float v = fsq[tid] * (1.0f / NN) - m * m;
      float a = bng[tid] * rsqrtf(v + BN_EPS);
      scl[tid] = a;
      shf[tid] = bnb[tid] - m * a;
    }
  }
  __syncthreads();
  if (STATS) {
    float clocal = 0.f;
    for (int i = tid; i < K * HID; i += 256) {
      int k = i >> 6;                      // HID == 64; k wave-uniform
      float w = W[i];                      // coalesced
      clocal += shf[k] * w;
      Wl[i] = w * scl[k];
    }
    atomicAdd(&cvec[tid & 63], clocal);    // feature index fixed per thread
  } else {
    for (int i = tid; i < K * HID; i += 256) Wl[i] = W[i];
  }
  __syncthreads();

  int lane = tid & 63;
  int wid = tid >> 6;
  int row0 = blockIdx.x * 16 + wid * 4;    // NN % 16 == 0, no tail
  int ur = __builtin_amdgcn_readfirstlane(row0);
  const float* xr0 = x + (size_t)ur * K;   // uniform -> scalar loads
  const float* xr1 = xr0 + K;
  const float* xr2 = xr0 + 2 * K;
  const float* xr3 = xr0 + 3 * K;
  float cv = cvec[lane];
  float a0 = cv, a1 = cv, a2 = cv, a3 = cv;
#pragma unroll 4
  for (int k = 0; k < K; k += 4) {
    float4 v0 = *(const float4*)(xr0 + k);
    float4 v1 = *(const float4*)(xr1 + k);
    float4 v2 = *(const float4*)(xr2 + k);
    float4 v3 = *(const float4*)(xr3 + k);
    float w0 = Wl[(k + 0) * HID + lane];   // stride-1 across lanes
    float w1 = Wl[(k + 1) * HID + lane];
    float w2 = Wl[(k + 2) * HID + lane];
    float w3 = Wl[(k + 3) * HID + lane];
    a0 = fmaf(v0.x, w0, a0); a0 = fmaf(v0.y, w1, a0);
    a0 = fmaf(v0.z, w2, a0); a0 = fmaf(v0.w, w3, a0);
    a1 = fmaf(v1.x, w0, a1); a1 = fmaf(v1.y, w1, a1);
    a1 = fmaf(v1.z, w2, a1); a1 = fmaf(v1.w, w3, a1);
    a2 = fmaf(v2.x, w0, a2); a2 = fmaf(v2.y, w1, a2);
    a2 = fmaf(v2.z, w2, a2); a2 = fmaf(v2.w, w3, a2);
    a3 = fmaf(v3.x, w0, a3); a3 = fmaf(v3.y, w1, a3);
    a3 = fmaf(v3.z, w2, a3); a3 = fmaf(v3.w, w3, a3);
  }

  float asl = a_s[lane], adl = a_d[lane];
  h[(size_t)(row0 + 0) * HID + lane] = a0;
  h[(size_t)(row0 + 1) * HID + lane] = a1;
  h[(size_t)(row0 + 2) * HID + lane] = a2;
  h[(size_t)(row0 + 3) * HID + lane] = a3;
  float s0 = a0 * asl, d0 = a0 * adl;
  float s1 = a1 * asl, d1 = a1 * adl;
  float s2 = a2 * asl, d2 = a2 * adl;
  float s3 = a3 * asl, d3 = a3 * adl;
  for (int o = 32; o; o >>= 1) {
    s0 += __shfl_xor(s0, o); d0 += __shfl_xor(d0, o);
    s1 += __shfl_xor(s1, o); d1 += __shfl_xor(d1, o);
    s2 += __shfl_xor(s2, o); d2 += __shfl_xor(d2, o);
    s3 += __shfl_xor(s3, o); d3 += __shfl_xor(d3, o);
  }
  if (lane == 0) {
    sv_out[row0 + 0] = s0; dv_out[row0 + 0] = d0;
    sv_out[row0 + 1] = s1; dv_out[row0 + 1] = d1;
    sv_out[row0 + 2] = s2; dv_out[row0 + 2] = d2;
    sv_out[row0 + 3] = s3; dv_out[row0 + 3] = d3;
  }
}

// ---------------- fused per-dst GAT aggregation ----------------
// wave per node. Softmax phase: lane=edge (alpha=0 for lane>=deg).
// Gather phase: DUAL-EDGE float2 layout (R9 config, best measured:
// 123us, 28 VGPR, 62% occ; R10 quad-edge float4 regressed via VGPR 40 ->
// 44% occ). Lanes 0-31 take even-slot edges, 32-63 odd; float2/lane.
// FETCH ~198MB = 8 XCD x 25.6MB h = compulsory-traffic floor for fp32 h.
__global__ __launch_bounds__(256) void gat_agg_k(
    const int* __restrict__ rowptr, const int* __restrict__ esrc,
    const float* __restrict__ s, const float* __restrict__ d,
    const float* __restrict__ h, const float* __restrict__ bias,
    float* __restrict__ y, float* __restrict__ fsum, float* __restrict__ fsq) {
  __shared__ float lsum[HID], lsq[HID];
  int tid = threadIdx.x;
  if (tid < HID) { lsum[tid] = 0.f; lsq[tid] = 0.f; }
  __syncthreads();
  int lane = tid & 63;
  int half = lane >> 5;
  int fl = (lane & 31) * 2;
  float2 bv = *(const float2*)&bias[fl];
  float2 ls = {0.f, 0.f}, lq = {0.f, 0.f};
  int wave = blockIdx.x * 4 + (tid >> 6);
  int nwaves = gridDim.x * 4;
  for (int node = wave; node < NN; node += nwaves) {
    int start = rowptr[node], end = rowptr[node + 1];
    int deg = end - start;
    float dn = d[node];
    float2 acc = {0.f, 0.f};
    if (deg <= 64) {
      int j = start + (lane < deg ? lane : 0);
      int sj = esrc[j];                         // coalesced
      float e = lrelu(s[sj] + dn);
      float ev = (lane < deg) ? e : -INFINITY;
      float m = ev;
      for (int o = 32; o; o >>= 1) m = fmaxf(m, __shfl_xor(m, o));
      float w = (lane < deg) ? __expf(e - m) : 0.f;
      float wsum = w;
      for (int o = 32; o; o >>= 1) wsum += __shfl_xor(wsum, o);
      float alpha = w / wsum;                   // 0 for slots >= deg
      for (int t = 0; t < deg; t += 8) {
#pragma unroll
        for (int i = 0; i < 4; ++i) {
          int e0 = t + 2 * i;
          int p0 = __builtin_amdgcn_readlane(sj, e0);
          int p1 = __builtin_amdgcn_readlane(sj, e0 + 1);
          float a0 = readlane_f(alpha, e0);
          float a1 = readlane_f(alpha, e0 + 1);
          int ps = half ? p1 : p0;
          float aw = half ? a1 : a0;
          float2 hv = *(const float2*)&h[(size_t)ps * HID + fl];
          acc.x = fmaf(aw, hv.x, acc.x);
          acc.y = fmaf(aw, hv.y, acc.y);
        }
      }
    } else {
      // generic chunked path (deg > 64): same dual-edge gather per chunk
      float m = -INFINITY;
      for (int j = start + lane; j < end; j += 64)
        m = fmaxf(m, lrelu(s[esrc[j]] + dn));
      for (int o = 32; o; o >>= 1) m = fmaxf(m, __shfl_xor(m, o));
      float wsum = 0.f;
      for (int j = start + lane; j < end; j += 64)
        wsum += __expf(lrelu(s[esrc[j]] + dn) - m);
      for (int o = 32; o; o >>= 1) wsum += __shfl_xor(wsum, o);
      float inv = 1.0f / wsum;
      for (int cb = start; cb < end; cb += 64) {
        int cc = min(64, end - cb);
        int j = cb + (lane < cc ? lane : 0);
        int sj = esrc[j];
        float alpha = (lane < cc) ? __expf(lrelu(s[sj] + dn) - m) * inv : 0.f;
        for (int t = 0; t < cc; t += 8) {
#pragma unroll
          for (int i = 0; i < 4; ++i) {
            int e0 = t + 2 * i;
            int p0 = __builtin_amdgcn_readlane(sj, e0);
            int p1 = __builtin_amdgcn_readlane(sj, e0 + 1);
            float a0 = readlane_f(alpha, e0);
            float a1 = readlane_f(alpha, e0 + 1);
            int ps = half ? p1 : p0;
            float aw = half ? a1 : a0;
            float2 hv = *(const float2*)&h[(size_t)ps * HID + fl];
            acc.x = fmaf(aw, hv.x, acc.x);
            acc.y = fmaf(aw, hv.y, acc.y);
          }
        }
      }
    }
    // cross-half combine: both halves end with the full per-feature sum
    acc.x += __shfl_xor(acc.x, 32);
    acc.y += __shfl_xor(acc.y, 32);
    float vx = fmaxf(acc.x + bv.x, 0.f);
    float vy = fmaxf(acc.y + bv.y, 0.f);
    if (half == 0) {
      *(float2*)&y[(size_t)node * HID + fl] = make_float2(vx, vy);
      ls.x += vx; ls.y += vy;
      lq.x += vx * vx; lq.y += vy * vy;
    }
  }
  if (lane < 32) {
    atomicAdd(&lsum[fl + 0], ls.x);
    atomicAdd(&lsum[fl + 1], ls.y);
    atomicAdd(&lsq[fl + 0], lq.x);
    atomicAdd(&lsq[fl + 1], lq.y);
  }
  __syncthreads();
  if (tid < HID) { atomicAdd(&fsum[tid], lsum[tid]); atomicAdd(&fsq[tid], lsq[tid]); }
}

// segmented pool over sorted batch: wave per contiguous node range; register
// accumulate per graph run; one 64-lane atomic flush per run. Also counts.
__global__ __launch_bounds__(256) void pool_k(
    const float* __restrict__ y, const int* __restrict__ batch,
    float* __restrict__ pooled, float* __restrict__ cnt) {
  int wid = blockIdx.x * 4 + (threadIdx.x >> 6);
  int lane = threadIdx.x & 63;
  int nw = gridDim.x * 4;
  int per = (NN + nw - 1) / nw;
  int lo = wid * per, hi = min(lo + per, NN);
  if (lo >= hi) return;
  int g = batch[lo];
  float acc = 0.f, c = 0.f;
  for (int node = lo; node < hi; ++node) {
    int bg = batch[node];                 // wave-uniform
    if (bg != g) {
      atomicAdd(&pooled[g * HID + lane], acc);
      if (lane == 0) atomicAdd(&cnt[g], c);
      g = bg; acc = 0.f; c = 0.f;
    }
    acc += y[(size_t)node * HID + lane];
    c += 1.f;
  }
  atomicAdd(&pooled[g * HID + lane], acc);
  if (lane == 0) atomicAdd(&cnt[g], c);
}

// one block (64 threads) per graph: BN2 affine (computed inline from
// fsum2/fsq2 -- bn_params kernel deleted) + mean + full MLP head.
__global__ __launch_bounds__(64) void mlp_head(
    const float* __restrict__ pooled, const float* __restrict__ cnt,
    const float* __restrict__ fsum, const float* __restrict__ fsq,
    const float* __restrict__ bng, const float* __restrict__ bnb,
    const float* __restrict__ m1w, const float* __restrict__ m1b,
    const float* __restrict__ m2w, const float* __restrict__ m2b,
    const float* __restrict__ m3w, const float* __restrict__ m3b,
    const float* __restrict__ m4w, const float* __restrict__ m4b,
    float* __restrict__ out) {
  __shared__ float p[64], z1[64], z2[16], z3[8];
  int g = blockIdx.x, f = threadIdx.x;
  float m = fsum[f] * (1.0f / NN);
  float v = fsq[f] * (1.0f / NN) - m * m;
  float a = bng[f] * rsqrtf(v + BN_EPS);
  float c = bnb[f] - m * a;
  float cv = fmaxf(cnt[g], 1.0f);
  p[f] = a * pooled[g * 64 + f] / cv + c;
  __syncthreads();
  float a1 = m1b[f];
  for (int k = 0; k < 64; ++k) a1 += p[k] * m1w[k * 64 + f];
  z1[f] = fmaxf(a1, 0.f);
  __syncthreads();
  if (f < 16) {
    float a2 = m2b[f];
    for (int k = 0; k < 64; ++k) a2 += z1[k] * m2w[k * 16 + f];
    z2[f] = fmaxf(a2, 0.f);
  }
  __syncthreads();
  if (f < 8) {
    float a3 = m3b[f];
    for (int k = 0; k < 16; ++k) a3 += z2[k] * m3w[k * 8 + f];
    z3[f] = fmaxf(a3, 0.f);
  }
  __syncthreads();
  if (f < 10) {
    float a4 = m4b[f];
    for (int k = 0; k < 8; ++k) a4 += z3[k] * m4w[k * 10 + f];
    out[g * 10 + f] = a4;
  }
}

extern "C" void kernel_launch(void* const* d_in, const int* in_sizes, int n_in,
                              void* d_out, int out_size, void* d_ws, size_t ws_size,
                              hipStream_t stream) {
  const float* x   = (const float*)d_in[0];
  const int*   ei  = (const int*)d_in[1];
  const int*   bat = (const int*)d_in[2];
  const float* W1  = (const float*)d_in[3];
  const float* as1 = (const float*)d_in[4];
  const float* ad1 = (const float*)d_in[5];
  const float* b1  = (const float*)d_in[6];
  const float* W2  = (const float*)d_in[7];
  const float* as2 = (const float*)d_in[8];
  const float* ad2 = (const float*)d_in[9];
  const float* b2  = (const float*)d_in[10];
  const float* bng = (const float*)d_in[11];
  const float* bnb = (const float*)d_in[12];
  const float* m1w = (const float*)d_in[13];
  const float* m1b = (const float*)d_in[14];
  const float* m2w = (const float*)d_in[15];
  const float* m2b = (const float*)d_in[16];
  const float* m3w = (const float*)d_in[17];
  const float* m3b = (const float*)d_in[18];
  const float* m4w = (const float*)d_in[19];
  const float* m4b = (const float*)d_in[20];
  float* out = (float*)d_out;

  float* ws = (float*)d_ws;
  size_t off = 0;
  float* hbuf = ws + off; off += (size_t)NN * HID;   // GEMM output h (aliases stage)
  float* ybuf = ws + off; off += (size_t)NN * HID;   // layer output y
  float* sbuf = ws + off; off += NN;                 // alpha_s
  float* dbuf = ws + off; off += NN;                 // alpha_d
  int* deg    = (int*)(ws + off); off += NN;
  int* rowptr = (int*)(ws + off); off += NN + 1;
  int* esrc   = (int*)(ws + off); off += ET;         // CSR: src per dst-sorted edge
  int* bsum   = (int*)(ws + off); off += SCAN_NB;
  int* bbase  = (int*)(ws + off); off += SCAN_NB;
  int* bukcur = (int*)(ws + off); off += NBUK;
  float* fsum1 = ws + off; off += HID;
  float* fsq1  = ws + off; off += HID;
  float* fsum2 = ws + off; off += HID;
  float* fsq2  = ws + off; off += HID;
  float* pooled = ws + off; off += (size_t)NG * HID; // raw per-graph sums
  float* cnt  = ws + off; off += NG;
  int2* stage = (int2*)hbuf;  // 16MB staging aliases hbuf (free until gemm1)

  dim3 b256(256);
  const int gemmGrid = NN / 16;                      // 6250, exact
  const int p1Grid = (ET + P1_CHUNK - 1) / P1_CHUNK; // 416
  const int aggGrid = 2048;

  // ---------- CSR build (shared by both layers) ----------
  init_k<<<(NN + 255) / 256, b256, 0, stream>>>(deg, bukcur, fsum1, fsq1,
                                                fsum2, fsq2, pooled, cnt);
  part1_k<<<p1Grid, b256, 0, stream>>>(ei, deg, bukcur, stage);
  scan_bsums_k<<<SCAN_NB, SCAN_T, 0, stream>>>(deg, bsum);
  scan_bbase_k<<<1, 64, 0, stream>>>(bsum, bbase);
  scan_final_k<<<SCAN_NB, SCAN_T, 0, stream>>>(deg, bbase, rowptr);
  part2_k<<<NBUK, b256, 0, stream>>>(stage, bukcur, rowptr, esrc);

  // ---------- layer 1 ----------
  gemm_att<INF_, false><<<gemmGrid, b256, 0, stream>>>(
      x, nullptr, nullptr, nullptr, nullptr, W1, as1, ad1, hbuf, sbuf, dbuf);
  gat_agg_k<<<aggGrid, b256, 0, stream>>>(rowptr, esrc, sbuf, dbuf, hbuf, b1,
                                          ybuf, fsum1, fsq1);

  // ---------- layer 2 (BN1 affine computed inline in gemm) ----------
  gemm_att<HID, true><<<gemmGrid, b256, 0, stream>>>(
      ybuf, fsum1, fsq1, bng, bnb, W2, as2, ad2, hbuf, sbuf, dbuf);
  gat_agg_k<<<aggGrid, b256, 0, stream>>>(rowptr, esrc, sbuf, dbuf, hbuf, b2,
                                          ybuf, fsum2, fsq2);

  // ---------- pool (segmented, sorted batch) + MLP (BN2 inline) ----------
  pool_k<<<1024, b256, 0, stream>>>(ybuf, bat, pooled, cnt);
  mlp_head<<<NG, 64, 0, stream>>>(pooled, cnt, fsum2, fsq2, bng, bnb,
                                  m1w, m1b, m2w, m2b, m3w, m3b, m4w, m4b, out);
}

// Round 14
// 400.191 us; speedup vs baseline: 1.4945x; 1.1856x over previous
//
#include <hip/hip_runtime.h>

// Problem constants (match reference)
#define NN   100000              // nodes
#define NE   1600000             // edges before self loops
#define ET   (NE + NN)           // edges incl. self loops
#define INF_ 128                 // input features
#define HID  64                  // hidden
#define NG   256                 // graphs
#define BN_EPS 1e-5f
#define NEG  0.2f

// bucket partition geometry (CSR fill)
#define BSPAN_LOG 8
#define BSPAN     (1 << BSPAN_LOG)                 // 256 dst nodes per bucket
#define NBUK      ((NN + BSPAN - 1) / BSPAN)       // 391
#define BUKCAP    5120                             // >= mu+12sigma of bucket load
#define P1_EPT    16
#define P1_CHUNK  (256 * P1_EPT)                   // 4096 edges per block

__device__ __forceinline__ float lrelu(float v) { return v > 0.f ? v : NEG * v; }

__device__ __forceinline__ float readlane_f(float v, int l) {
  return __int_as_float(__builtin_amdgcn_readlane(__float_as_int(v), l));
}

// ---------------- unified init ----------------
__global__ __launch_bounds__(256) void init_k(
    int* __restrict__ bukcur,
    float* __restrict__ fsum1, float* __restrict__ fsq1,
    float* __restrict__ fsum2, float* __restrict__ fsq2,
    float* __restrict__ pooled, float* __restrict__ cnt) {
  int i = blockIdx.x * 256 + threadIdx.x;
  if (i < NBUK) bukcur[i] = i * BUKCAP;
  if (i < HID) { fsum1[i] = 0.f; fsq1[i] = 0.f; fsum2[i] = 0.f; fsq2[i] = 0.f; }
  if (i < NG * HID) pooled[i] = 0.f;
  if (i < NG) cnt[i] = 0.f;
}

// ---------------- CSR build (edges sorted by dst) ----------------
// phase 1: partition edges into fixed-capacity dst-buckets (base b*BUKCAP).
// LDS histogram -> one global reservation per bucket per block ->
// contiguous staging runs (8B int2). No global deg histogram (R13: per-dst
// counts recovered in part2 from the L2-resident bucket window).
__global__ __launch_bounds__(256) void part1_k(const int* __restrict__ ei,
                                               int* __restrict__ bukcur,
                                               int2* __restrict__ stage) {
  __shared__ int hist[NBUK];
  __shared__ int base[NBUK];
  int t = threadIdx.x;
  for (int b = t; b < NBUK; b += 256) hist[b] = 0;
  __syncthreads();
  int chunk = blockIdx.x * P1_CHUNK;
  int myb[P1_EPT], myr[P1_EPT], mys[P1_EPT], myd[P1_EPT];
#pragma unroll
  for (int it = 0; it < P1_EPT; ++it) {
    int i = chunk + it * 256 + t;
    bool v = i < ET;
    int src = 0, dst = 0;
    if (v) {
      src = i < NE ? ei[i] : i - NE;
      dst = i < NE ? ei[NE + i] : i - NE;
    }
    myb[it] = v ? (dst >> BSPAN_LOG) : -1;
    mys[it] = src;
    myd[it] = dst;
    myr[it] = v ? atomicAdd(&hist[dst >> BSPAN_LOG], 1) : 0;
  }
  __syncthreads();
  for (int b = t; b < NBUK; b += 256)
    base[b] = hist[b] ? atomicAdd(&bukcur[b], hist[b]) : 0;
  __syncthreads();
#pragma unroll
  for (int it = 0; it < P1_EPT; ++it)
    if (myb[it] >= 0)
      stage[base[myb[it]] + myr[it]] = make_int2(mys[it], myd[it]);
}

// single-block exclusive scan over the 391 bucket counts -> esrc bases
__global__ __launch_bounds__(512) void bukscan_k(const int* __restrict__ bukcur,
                                                 int* __restrict__ bukbase,
                                                 int* __restrict__ rowptr) {
  __shared__ int sh[512];
  int t = threadIdx.x;
  int c = (t < NBUK) ? (bukcur[t] - t * BUKCAP) : 0;
  sh[t] = c;
  __syncthreads();
  for (int off = 1; off < 512; off <<= 1) {
    int add = (t >= off) ? sh[t - off] : 0;
    __syncthreads();
    sh[t] += add;
    __syncthreads();
  }
  if (t < NBUK) bukbase[t] = sh[t] - c;
  if (t == 0) rowptr[NN] = ET;
}

// phase 2: one block per bucket. Pass A: count per-dst into LDS from the
// bucket's stage window (~17KB, L2-resident). Pass B: 256-wide LDS scan +
// bucket base -> rowptr for this bucket's 256 nodes. Pass C: re-read stage
// (L2 hit), scatter esrc via LDS cursors. No global deg/scan chain.
__global__ __launch_bounds__(256) void part2_k(const int2* __restrict__ stage,
                                               const int* __restrict__ bukcur,
                                               const int* __restrict__ bukbase,
                                               int* __restrict__ rowptr,
                                               int* __restrict__ esrc) {
  __shared__ int lcnt[BSPAN];
  __shared__ int lscan[BSPAN];
  int b = blockIdx.x;
  int node0 = b << BSPAN_LOG;
  int t = threadIdx.x;
  lcnt[t] = 0;
  __syncthreads();
  int s = b * BUKCAP, e = bukcur[b];
  for (int i = s + t; i < e; i += 256)
    atomicAdd(&lcnt[stage[i].y - node0], 1);
  __syncthreads();
  int v = lcnt[t];
  lscan[t] = v;
  __syncthreads();
  for (int off = 1; off < 256; off <<= 1) {
    int add = (t >= off) ? lscan[t - off] : 0;
    __syncthreads();
    lscan[t] += add;
    __syncthreads();
  }
  int excl = bukbase[b] + lscan[t] - v;    // exclusive prefix + bucket base
  if (node0 + t < NN) rowptr[node0 + t] = excl;
  lcnt[t] = excl;                          // reuse as cursor
  __syncthreads();
  for (int i = s + t; i < e; i += 256) {
    int2 p = stage[i];
    int pos = atomicAdd(&lcnt[p.y - node0], 1);
    esrc[pos] = p.x;
  }
}

// ---------------- GEMM + attention logits (v4) ----------------
// h = (x*bnA+bnC) @ W ; alpha_s = h.as ; alpha_d = h.ad
// STATS=true: BN affine computed inline from fsum/fsq/g/b and folded into
// the LDS weight copy; cvec = bnC@W. W in LDS [k][f] (lane stride-1,
// conflict-free). x rows are WAVE-UNIFORM via readfirstlane -> scalar
// loads; FMA takes the uniform operand from SGPR.
// NOTE R5: 8 rows/wave -> 256 VGPR -> occupancy collapse. Keep 4 rows.
// NOTE R7: per-lane b128 at LDS stride K+4 was an 8-way bank conflict.
// NOTE R8-R10: x via VGPR+readlane = SGPR-hazard stalls; v3's LDS xt =
// LDS-throughput bound. Scalar-load x avoids both.
template <int K, bool STATS>
__global__ __launch_bounds__(256) void gemm_att(
    const float* __restrict__ x,
    const float* __restrict__ fsum, const float* __restrict__ fsq,
    const float* __restrict__ bng, const float* __restrict__ bnb,
    const float* __restrict__ W,
    const float* __restrict__ a_s, const float* __restrict__ a_d,
    float* __restrict__ h, float* __restrict__ sv_out, float* __restrict__ dv_out) {
  __shared__ float Wl[K * HID];          // [k][f]: lane reads stride-1
  __shared__ float cvec[HID];
  __shared__ float scl[HID], shf[HID];   // only used when STATS (K==HID)
  int tid = threadIdx.x;
  if (tid < HID) {
    cvec[tid] = 0.f;
    if (STATS) {
      float m = fsum[tid] * (1.0f / NN);
      float v = fsq[tid] * (1.0f / NN) - m * m;
      float a = bng[tid] * rsqrtf(v + BN_EPS);
      scl[tid] = a;
      shf[tid] = bnb[tid] - m * a;
    }
  }
  __syncthreads();
  if (STATS) {
    float clocal = 0.f;
    for (int i = tid; i < K * HID; i += 256) {
      int k = i >> 6;                      // HID == 64; k wave-uniform
      float w = W[i];                      // coalesced
      clocal += shf[k] * w;
      Wl[i] = w * scl[k];
    }
    atomicAdd(&cvec[tid & 63], clocal);    // feature index fixed per thread
  } else {
    for (int i = tid; i < K * HID; i += 256) Wl[i] = W[i];
  }
  __syncthreads();

  int lane = tid & 63;
  int wid = tid >> 6;
  int row0 = blockIdx.x * 16 + wid * 4;    // NN % 16 == 0, no tail
  int ur = __builtin_amdgcn_readfirstlane(row0);
  const float* xr0 = x + (size_t)ur * K;   // uniform -> scalar loads
  const float* xr1 = xr0 + K;
  const float* xr2 = xr0 + 2 * K;
  const float* xr3 = xr0 + 3 * K;
  float cv = cvec[lane];
  float a0 = cv, a1 = cv, a2 = cv, a3 = cv;
#pragma unroll 4
  for (int k = 0; k < K; k += 4) {
    float4 v0 = *(const float4*)(xr0 + k);
    float4 v1 = *(const float4*)(xr1 + k);
    float4 v2 = *(const float4*)(xr2 + k);
    float4 v3 = *(const float4*)(xr3 + k);
    float w0 = Wl[(k + 0) * HID + lane];   // stride-1 across lanes
    float w1 = Wl[(k + 1) * HID + lane];
    float w2 = Wl[(k + 2) * HID + lane];
    float w3 = Wl[(k + 3) * HID + lane];
    a0 = fmaf(v0.x, w0, a0); a0 = fmaf(v0.y, w1, a0);
    a0 = fmaf(v0.z, w2, a0); a0 = fmaf(v0.w, w3, a0);
    a1 = fmaf(v1.x, w0, a1); a1 = fmaf(v1.y, w1, a1);
    a1 = fmaf(v1.z, w2, a1); a1 = fmaf(v1.w, w3, a1);
    a2 = fmaf(v2.x, w0, a2); a2 = fmaf(v2.y, w1, a2);
    a2 = fmaf(v2.z, w2, a2); a2 = fmaf(v2.w, w3, a2);
    a3 = fmaf(v3.x, w0, a3); a3 = fmaf(v3.y, w1, a3);
    a3 = fmaf(v3.z, w2, a3); a3 = fmaf(v3.w, w3, a3);
  }

  float asl = a_s[lane], adl = a_d[lane];
  h[(size_t)(row0 + 0) * HID + lane] = a0;
  h[(size_t)(row0 + 1) * HID + lane] = a1;
  h[(size_t)(row0 + 2) * HID + lane] = a2;
  h[(size_t)(row0 + 3) * HID + lane] = a3;
  float s0 = a0 * asl, d0 = a0 * adl;
  float s1 = a1 * asl, d1 = a1 * adl;
  float s2 = a2 * asl, d2 = a2 * adl;
  float s3 = a3 * asl, d3 = a3 * adl;
  for (int o = 32; o; o >>= 1) {
    s0 += __shfl_xor(s0, o); d0 += __shfl_xor(d0, o);
    s1 += __shfl_xor(s1, o); d1 += __shfl_xor(d1, o);
    s2 += __shfl_xor(s2, o); d2 += __shfl_xor(d2, o);
    s3 += __shfl_xor(s3, o); d3 += __shfl_xor(d3, o);
  }
  if (lane == 0) {
    sv_out[row0 + 0] = s0; dv_out[row0 + 0] = d0;
    sv_out[row0 + 1] = s1; dv_out[row0 + 1] = d1;
    sv_out[row0 + 2] = s2; dv_out[row0 + 2] = d2;
    sv_out[row0 + 3] = s3; dv_out[row0 + 3] = d3;
  }
}

// ---------------- per-node GAT aggregation core ----------------
// Softmax: lane=edge (alpha=0 for lane>=deg). Gather: DUAL-EDGE float2
// (R9 config, best measured; R10 quad-edge regressed via VGPR->occupancy).
// Returns the full per-feature sum (both halves identical after xor-32).
__device__ __forceinline__ float2 gat_node(
    int node, const int* __restrict__ rowptr, const int* __restrict__ esrc,
    const float* __restrict__ s, const float* __restrict__ d,
    const float* __restrict__ h, int lane, int half, int fl) {
  int start = rowptr[node], end = rowptr[node + 1];
  int deg = end - start;
  float dn = d[node];
  float2 acc = {0.f, 0.f};
  if (deg <= 64) {
    int j = start + (lane < deg ? lane : 0);
    int sj = esrc[j];                         // coalesced
    float e = lrelu(s[sj] + dn);
    float ev = (lane < deg) ? e : -INFINITY;
    float m = ev;
    for (int o = 32; o; o >>= 1) m = fmaxf(m, __shfl_xor(m, o));
    float w = (lane < deg) ? __expf(e - m) : 0.f;
    float wsum = w;
    for (int o = 32; o; o >>= 1) wsum += __shfl_xor(wsum, o);
    float alpha = w / wsum;                   // 0 for slots >= deg
    for (int t = 0; t < deg; t += 8) {
#pragma unroll
      for (int i = 0; i < 4; ++i) {
        int e0 = t + 2 * i;
        int p0 = __builtin_amdgcn_readlane(sj, e0);
        int p1 = __builtin_amdgcn_readlane(sj, e0 + 1);
        float a0 = readlane_f(alpha, e0);
        float a1 = readlane_f(alpha, e0 + 1);
        int ps = half ? p1 : p0;
        float aw = half ? a1 : a0;
        float2 hv = *(const float2*)&h[(size_t)ps * HID + fl];
        acc.x = fmaf(aw, hv.x, acc.x);
        acc.y = fmaf(aw, hv.y, acc.y);
      }
    }
  } else {
    float m = -INFINITY;
    for (int j = start + lane; j < end; j += 64)
      m = fmaxf(m, lrelu(s[esrc[j]] + dn));
    for (int o = 32; o; o >>= 1) m = fmaxf(m, __shfl_xor(m, o));
    float wsum = 0.f;
    for (int j = start + lane; j < end; j += 64)
      wsum += __expf(lrelu(s[esrc[j]] + dn) - m);
    for (int o = 32; o; o >>= 1) wsum += __shfl_xor(wsum, o);
    float inv = 1.0f / wsum;
    for (int cb = start; cb < end; cb += 64) {
      int cc = min(64, end - cb);
      int j = cb + (lane < cc ? lane : 0);
      int sj = esrc[j];
      float alpha = (lane < cc) ? __expf(lrelu(s[sj] + dn) - m) * inv : 0.f;
      for (int t = 0; t < cc; t += 8) {
#pragma unroll
        for (int i = 0; i < 4; ++i) {
          int e0 = t + 2 * i;
          int p0 = __builtin_amdgcn_readlane(sj, e0);
          int p1 = __builtin_amdgcn_readlane(sj, e0 + 1);
          float a0 = readlane_f(alpha, e0);
          float a1 = readlane_f(alpha, e0 + 1);
          int ps = half ? p1 : p0;
          float aw = half ? a1 : a0;
          float2 hv = *(const float2*)&h[(size_t)ps * HID + fl];
          acc.x = fmaf(aw, hv.x, acc.x);
          acc.y = fmaf(aw, hv.y, acc.y);
        }
      }
    }
  }
  acc.x += __shfl_xor(acc.x, 32);
  acc.y += __shfl_xor(acc.y, 32);
  return acc;
}

// layer-1 aggregation: strided nodes, writes y + BN stats.
__global__ __launch_bounds__(256) void gat_agg_k(
    const int* __restrict__ rowptr, const int* __restrict__ esrc,
    const float* __restrict__ s, const float* __restrict__ d,
    const float* __restrict__ h, const float* __restrict__ bias,
    float* __restrict__ y, float* __restrict__ fsum, float* __restrict__ fsq) {
  __shared__ float lsum[HID], lsq[HID];
  int tid = threadIdx.x;
  if (tid < HID) { lsum[tid] = 0.f; lsq[tid] = 0.f; }
  __syncthreads();
  int lane = tid & 63;
  int half = lane >> 5;
  int fl = (lane & 31) * 2;
  float2 bv = *(const float2*)&bias[fl];
  float2 ls = {0.f, 0.f}, lq = {0.f, 0.f};
  int wave = blockIdx.x * 4 + (tid >> 6);
  int nwaves = gridDim.x * 4;
  for (int node = wave; node < NN; node += nwaves) {
    float2 acc = gat_node(node, rowptr, esrc, s, d, h, lane, half, fl);
    float vx = fmaxf(acc.x + bv.x, 0.f);
    float vy = fmaxf(acc.y + bv.y, 0.f);
    if (half == 0) {
      *(float2*)&y[(size_t)node * HID + fl] = make_float2(vx, vy);
      ls.x += vx; ls.y += vy;
      lq.x += vx * vx; lq.y += vy * vy;
    }
  }
  if (lane < 32) {
    atomicAdd(&lsum[fl + 0], ls.x);
    atomicAdd(&lsum[fl + 1], ls.y);
    atomicAdd(&lsq[fl + 0], lq.x);
    atomicAdd(&lsq[fl + 1], lq.y);
  }
  __syncthreads();
  if (tid < HID) { atomicAdd(&fsum[tid], lsum[tid]); atomicAdd(&fsq[tid], lsq[tid]); }
}

// layer-2 aggregation + fused pooling: contiguous node ranges (batch is
// sorted) -> register-accumulate per graph run, one atomic flush per run.
// No y write (pool_k deleted; BN2 affine applied post-pool in mlp_head).
__global__ __launch_bounds__(256) void gat_agg_pool_k(
    const int* __restrict__ rowptr, const int* __restrict__ esrc,
    const float* __restrict__ s, const float* __restrict__ d,
    const float* __restrict__ h, const float* __restrict__ bias,
    const int* __restrict__ batch, float* __restrict__ pooled,
    float* __restrict__ cnt, float* __restrict__ fsum, float* __restrict__ fsq) {
  __shared__ float lsum[HID], lsq[HID];
  int tid = threadIdx.x;
  if (tid < HID) { lsum[tid] = 0.f; lsq[tid] = 0.f; }
  __syncthreads();
  int lane = tid & 63;
  int half = lane >> 5;
  int fl = (lane & 31) * 2;
  float2 bv = *(const float2*)&bias[fl];
  float2 ls = {0.f, 0.f}, lq = {0.f, 0.f};
  int wave = blockIdx.x * 4 + (tid >> 6);
  int nwaves = gridDim.x * 4;
  int per = (NN + nwaves - 1) / nwaves;
  int lo = wave * per, hi = min(lo + per, NN);
  if (lo < hi) {
    int g = batch[lo];
    float2 pacc = {0.f, 0.f};
    float c = 0.f;
    for (int node = lo; node < hi; ++node) {
      int bg = batch[node];                  // wave-uniform
      if (bg != g) {
        if (half == 0) {
          atomicAdd(&pooled[g * HID + fl + 0], pacc.x);
          atomicAdd(&pooled[g * HID + fl + 1], pacc.y);
        }
        if (lane == 0) atomicAdd(&cnt[g], c);
        g = bg; pacc.x = 0.f; pacc.y = 0.f; c = 0.f;
      }
      float2 acc = gat_node(node, rowptr, esrc, s, d, h, lane, half, fl);
      float vx = fmaxf(acc.x + bv.x, 0.f);
      float vy = fmaxf(acc.y + bv.y, 0.f);
      pacc.x += vx; pacc.y += vy; c += 1.f;
      if (half == 0) {
        ls.x += vx; ls.y += vy;
        lq.x += vx * vx; lq.y += vy * vy;
      }
    }
    if (half == 0) {
      atomicAdd(&pooled[g * HID + fl + 0], pacc.x);
      atomicAdd(&pooled[g * HID + fl + 1], pacc.y);
    }
    if (lane == 0) atomicAdd(&cnt[g], c);
  }
  if (lane < 32) {
    atomicAdd(&lsum[fl + 0], ls.x);
    atomicAdd(&lsum[fl + 1], ls.y);
    atomicAdd(&lsq[fl + 0], lq.x);
    atomicAdd(&lsq[fl + 1], lq.y);
  }
  __syncthreads();
  if (tid < HID) { atomicAdd(&fsum[tid], lsum[tid]); atomicAdd(&fsq[tid], lsq[tid]); }
}

// one block (64 threads) per graph: BN2 affine (inline from fsum2/fsq2)
// + mean + full MLP head.
__global__ __launch_bounds__(64) void mlp_head(
    const float* __restrict__ pooled, const float* __restrict__ cnt,
    const float* __restrict__ fsum, const float* __restrict__ fsq,
    const float* __restrict__ bng, const float* __restrict__ bnb,
    const float* __restrict__ m1w, const float* __restrict__ m1b,
    const float* __restrict__ m2w, const float* __restrict__ m2b,
    const float* __restrict__ m3w, const float* __restrict__ m3b,
    const float* __restrict__ m4w, const float* __restrict__ m4b,
    float* __restrict__ out) {
  __shared__ float p[64], z1[64], z2[16], z3[8];
  int g = blockIdx.x, f = threadIdx.x;
  float m = fsum[f] * (1.0f / NN);
  float v = fsq[f] * (1.0f / NN) - m * m;
  float a = bng[f] * rsqrtf(v + BN_EPS);
  float c = bnb[f] - m * a;
  float cv = fmaxf(cnt[g], 1.0f);
  p[f] = a * pooled[g * 64 + f] / cv + c;
  __syncthreads();
  float a1 = m1b[f];
  for (int k = 0; k < 64; ++k) a1 += p[k] * m1w[k * 64 + f];
  z1[f] = fmaxf(a1, 0.f);
  __syncthreads();
  if (f < 16) {
    float a2 = m2b[f];
    for (int k = 0; k < 64; ++k) a2 += z1[k] * m2w[k * 16 + f];
    z2[f] = fmaxf(a2, 0.f);
  }
  __syncthreads();
  if (f < 8) {
    float a3 = m3b[f];
    for (int k = 0; k < 16; ++k) a3 += z2[k] * m3w[k * 8 + f];
    z3[f] = fmaxf(a3, 0.f);
  }
  __syncthreads();
  if (f < 10) {
    float a4 = m4b[f];
    for (int k = 0; k < 8; ++k) a4 += z3[k] * m4w[k * 10 + f];
    out[g * 10 + f] = a4;
  }
}

extern "C" void kernel_launch(void* const* d_in, const int* in_sizes, int n_in,
                              void* d_out, int out_size, void* d_ws, size_t ws_size,
                              hipStream_t stream) {
  const float* x   = (const float*)d_in[0];
  const int*   ei  = (const int*)d_in[1];
  const int*   bat = (const int*)d_in[2];
  const float* W1  = (const float*)d_in[3];
  const float* as1 = (const float*)d_in[4];
  const float* ad1 = (const float*)d_in[5];
  const float* b1  = (const float*)d_in[6];
  const float* W2  = (const float*)d_in[7];
  const float* as2 = (const float*)d_in[8];
  const float* ad2 = (const float*)d_in[9];
  const float* b2  = (const float*)d_in[10];
  const float* bng = (const float*)d_in[11];
  const float* bnb = (const float*)d_in[12];
  const float* m1w = (const float*)d_in[13];
  const float* m1b = (const float*)d_in[14];
  const float* m2w = (const float*)d_in[15];
  const float* m2b = (const float*)d_in[16];
  const float* m3w = (const float*)d_in[17];
  const float* m3b = (const float*)d_in[18];
  const float* m4w = (const float*)d_in[19];
  const float* m4b = (const float*)d_in[20];
  float* out = (float*)d_out;

  float* ws = (float*)d_ws;
  size_t off = 0;
  float* hbuf = ws + off; off += (size_t)NN * HID;   // GEMM output h (aliases stage)
  float* ybuf = ws + off; off += (size_t)NN * HID;   // layer-1 output y
  float* sbuf = ws + off; off += NN;                 // alpha_s
  float* dbuf = ws + off; off += NN;                 // alpha_d
  int* rowptr = (int*)(ws + off); off += NN + 1;
  int* esrc   = (int*)(ws + off); off += ET;         // CSR: src per dst-sorted edge
  int* bukcur = (int*)(ws + off); off += NBUK;
  int* bukbase = (int*)(ws + off); off += NBUK;
  float* fsum1 = ws + off; off += HID;
  float* fsq1  = ws + off; off += HID;
  float* fsum2 = ws + off; off += HID;
  float* fsq2  = ws + off; off += HID;
  float* pooled = ws + off; off += (size_t)NG * HID; // raw per-graph sums
  float* cnt  = ws + off; off += NG;
  int2* stage = (int2*)hbuf;  // 16MB staging aliases hbuf (free until gemm1)

  dim3 b256(256);
  const int gemmGrid = NN / 16;                      // 6250, exact
  const int p1Grid = (ET + P1_CHUNK - 1) / P1_CHUNK; // 416
  const int aggGrid = 2048;

  // ---------- CSR build (shared by both layers) ----------
  init_k<<<(NG * HID + 255) / 256, b256, 0, stream>>>(bukcur, fsum1, fsq1,
                                                      fsum2, fsq2, pooled, cnt);
  part1_k<<<p1Grid, b256, 0, stream>>>(ei, bukcur, stage);
  bukscan_k<<<1, 512, 0, stream>>>(bukcur, bukbase, rowptr);
  part2_k<<<NBUK, b256, 0, stream>>>(stage, bukcur, bukbase, rowptr, esrc);

  // ---------- layer 1 ----------
  gemm_att<INF_, false><<<gemmGrid, b256, 0, stream>>>(
      x, nullptr, nullptr, nullptr, nullptr, W1, as1, ad1, hbuf, sbuf, dbuf);
  gat_agg_k<<<aggGrid, b256, 0, stream>>>(rowptr, esrc, sbuf, dbuf, hbuf, b1,
                                          ybuf, fsum1, fsq1);

  // ---------- layer 2 (BN1 inline in gemm; pooling fused into agg) ----------
  gemm_att<HID, true><<<gemmGrid, b256, 0, stream>>>(
      ybuf, fsum1, fsq1, bng, bnb, W2, as2, ad2, hbuf, sbuf, dbuf);
  gat_agg_pool_k<<<aggGrid, b256, 0, stream>>>(rowptr, esrc, sbuf, dbuf, hbuf,
                                               b2, bat, pooled, cnt, fsum2, fsq2);

  // ---------- MLP head (BN2 inline) ----------
  mlp_head<<<NG, 64, 0, stream>>>(pooled, cnt, fsum2, fsq2, bng, bnb,
                                  m1w, m1b, m2w, m2b, m3w, m3b, m4w, m4b, out);
}

// Round 15
// 386.851 us; speedup vs baseline: 1.5460x; 1.0345x over previous
//
#include <hip/hip_runtime.h>
#include <hip/hip_fp16.h>

// Problem constants (match reference)
#define NN   100000              // nodes
#define NE   1600000             // edges before self loops
#define ET   (NE + NN)           // edges incl. self loops
#define INF_ 128                 // input features
#define HID  64                  // hidden
#define NG   256                 // graphs
#define BN_EPS 1e-5f
#define NEG  0.2f

// bucket partition geometry (CSR fill)
#define BSPAN_LOG 8
#define BSPAN     (1 << BSPAN_LOG)                 // 256 dst nodes per bucket
#define NBUK      ((NN + BSPAN - 1) / BSPAN)       // 391
#define BUKCAP    5120                             // >= mu+12sigma of bucket load
#define P1_EPT    16
#define P1_CHUNK  (256 * P1_EPT)                   // 4096 edges per block

__device__ __forceinline__ float lrelu(float v) { return v > 0.f ? v : NEG * v; }

__device__ __forceinline__ float readlane_f(float v, int l) {
  return __int_as_float(__builtin_amdgcn_readlane(__float_as_int(v), l));
}

// ---------------- unified init ----------------
__global__ __launch_bounds__(256) void init_k(
    int* __restrict__ bukcur,
    float* __restrict__ fsum1, float* __restrict__ fsq1,
    float* __restrict__ fsum2, float* __restrict__ fsq2,
    float* __restrict__ pooled, float* __restrict__ cnt) {
  int i = blockIdx.x * 256 + threadIdx.x;
  if (i < NBUK) bukcur[i] = i * BUKCAP;
  if (i < HID) { fsum1[i] = 0.f; fsq1[i] = 0.f; fsum2[i] = 0.f; fsq2[i] = 0.f; }
  if (i < NG * HID) pooled[i] = 0.f;
  if (i < NG) cnt[i] = 0.f;
}

// ---------------- CSR build (edges sorted by dst) ----------------
// phase 1: partition edges into fixed-capacity dst-buckets (base b*BUKCAP).
// LDS histogram -> one global reservation per bucket per block ->
// contiguous staging runs (8B int2).
__global__ __launch_bounds__(256) void part1_k(const int* __restrict__ ei,
                                               int* __restrict__ bukcur,
                                               int2* __restrict__ stage) {
  __shared__ int hist[NBUK];
  __shared__ int base[NBUK];
  int t = threadIdx.x;
  for (int b = t; b < NBUK; b += 256) hist[b] = 0;
  __syncthreads();
  int chunk = blockIdx.x * P1_CHUNK;
  int myb[P1_EPT], myr[P1_EPT], mys[P1_EPT], myd[P1_EPT];
#pragma unroll
  for (int it = 0; it < P1_EPT; ++it) {
    int i = chunk + it * 256 + t;
    bool v = i < ET;
    int src = 0, dst = 0;
    if (v) {
      src = i < NE ? ei[i] : i - NE;
      dst = i < NE ? ei[NE + i] : i - NE;
    }
    myb[it] = v ? (dst >> BSPAN_LOG) : -1;
    mys[it] = src;
    myd[it] = dst;
    myr[it] = v ? atomicAdd(&hist[dst >> BSPAN_LOG], 1) : 0;
  }
  __syncthreads();
  for (int b = t; b < NBUK; b += 256)
    base[b] = hist[b] ? atomicAdd(&bukcur[b], hist[b]) : 0;
  __syncthreads();
#pragma unroll
  for (int it = 0; it < P1_EPT; ++it)
    if (myb[it] >= 0)
      stage[base[myb[it]] + myr[it]] = make_int2(mys[it], myd[it]);
}

// single-block exclusive scan over the 391 bucket counts -> esrc bases
__global__ __launch_bounds__(512) void bukscan_k(const int* __restrict__ bukcur,
                                                 int* __restrict__ bukbase,
                                                 int* __restrict__ rowptr) {
  __shared__ int sh[512];
  int t = threadIdx.x;
  int c = (t < NBUK) ? (bukcur[t] - t * BUKCAP) : 0;
  sh[t] = c;
  __syncthreads();
  for (int off = 1; off < 512; off <<= 1) {
    int add = (t >= off) ? sh[t - off] : 0;
    __syncthreads();
    sh[t] += add;
    __syncthreads();
  }
  if (t < NBUK) bukbase[t] = sh[t] - c;
  if (t == 0) rowptr[NN] = ET;
}

// phase 2: one block per bucket. Pass A: count per-dst into LDS from the
// bucket's stage window (~17KB, L2-resident). Pass B: 256-wide LDS scan +
// bucket base -> rowptr for this bucket's 256 nodes. Pass C: re-read stage
// (L2 hit), scatter esrc via LDS cursors.
__global__ __launch_bounds__(256) void part2_k(const int2* __restrict__ stage,
                                               const int* __restrict__ bukcur,
                                               const int* __restrict__ bukbase,
                                               int* __restrict__ rowptr,
                                               int* __restrict__ esrc) {
  __shared__ int lcnt[BSPAN];
  __shared__ int lscan[BSPAN];
  int b = blockIdx.x;
  int node0 = b << BSPAN_LOG;
  int t = threadIdx.x;
  lcnt[t] = 0;
  __syncthreads();
  int s = b * BUKCAP, e = bukcur[b];
  for (int i = s + t; i < e; i += 256)
    atomicAdd(&lcnt[stage[i].y - node0], 1);
  __syncthreads();
  int v = lcnt[t];
  lscan[t] = v;
  __syncthreads();
  for (int off = 1; off < 256; off <<= 1) {
    int add = (t >= off) ? lscan[t - off] : 0;
    __syncthreads();
    lscan[t] += add;
    __syncthreads();
  }
  int excl = bukbase[b] + lscan[t] - v;    // exclusive prefix + bucket base
  if (node0 + t < NN) rowptr[node0 + t] = excl;
  lcnt[t] = excl;                          // reuse as cursor
  __syncthreads();
  for (int i = s + t; i < e; i += 256) {
    int2 p = stage[i];
    int pos = atomicAdd(&lcnt[p.y - node0], 1);
    esrc[pos] = p.x;
  }
}

// ---------------- GEMM + attention logits (v4 + fp16 h) ----------------
// h = (x*bnA+bnC) @ W ; alpha_s = h.as ; alpha_d = h.ad
// h is written FP16 (gather traffic halves; R14: agg pinned to its L2-miss
// traffic at 198MB, so bytes are the lever). s/d logits are computed from
// the FP32 accumulators (full precision), y stays fp32.
// STATS=true: BN affine computed inline from fsum/fsq/g/b and folded into
// the LDS weight copy; cvec = bnC@W. W in LDS [k][f] (lane stride-1,
// conflict-free). x rows are WAVE-UNIFORM via readfirstlane -> scalar
// loads; FMA takes the uniform operand from SGPR.
// NOTE R5: 8 rows/wave -> 256 VGPR -> occupancy collapse. Keep 4 rows.
// NOTE R7: per-lane b128 at LDS stride K+4 was an 8-way bank conflict.
// NOTE R8-R10: x via VGPR+readlane = SGPR-hazard stalls; LDS xt =
// LDS-throughput bound. Scalar-load x avoids both.
template <int K, bool STATS>
__global__ __launch_bounds__(256) void gemm_att(
    const float* __restrict__ x,
    const float* __restrict__ fsum, const float* __restrict__ fsq,
    const float* __restrict__ bng, const float* __restrict__ bnb,
    const float* __restrict__ W,
    const float* __restrict__ a_s, const float* __restrict__ a_d,
    __half* __restrict__ h, float* __restrict__ sv_out, float* __restrict__ dv_out) {
  __shared__ float Wl[K * HID];          // [k][f]: lane reads stride-1
  __shared__ float cvec[HID];
  __shared__ float scl[HID], shf[HID];   // only used when STATS (K==HID)
  int tid = threadIdx.x;
  if (tid < HID) {
    cvec[tid] = 0.f;
    if (STATS) {
      float m = fsum[tid] * (1.0f / NN);
      float v = fsq[tid] * (1.0f / NN) - m * m;
      float a = bng[tid] * rsqrtf(v + BN_EPS);
      scl[tid] = a;
      shf[tid] = bnb[tid] - m * a;
    }
  }
  __syncthreads();
  if (STATS) {
    float clocal = 0.f;
    for (int i = tid; i < K * HID; i += 256) {
      int k = i >> 6;                      // HID == 64; k wave-uniform
      float w = W[i];                      // coalesced
      clocal += shf[k] * w;
      Wl[i] = w * scl[k];
    }
    atomicAdd(&cvec[tid & 63], clocal);    // feature index fixed per thread
  } else {
    for (int i = tid; i < K * HID; i += 256) Wl[i] = W[i];
  }
  __syncthreads();

  int lane = tid & 63;
  int wid = tid >> 6;
  int row0 = blockIdx.x * 16 + wid * 4;    // NN % 16 == 0, no tail
  int ur = __builtin_amdgcn_readfirstlane(row0);
  const float* xr0 = x + (size_t)ur * K;   // uniform -> scalar loads
  const float* xr1 = xr0 + K;
  const float* xr2 = xr0 + 2 * K;
  const float* xr3 = xr0 + 3 * K;
  float cv = cvec[lane];
  float a0 = cv, a1 = cv, a2 = cv, a3 = cv;
#pragma unroll 4
  for (int k = 0; k < K; k += 4) {
    float4 v0 = *(const float4*)(xr0 + k);
    float4 v1 = *(const float4*)(xr1 + k);
    float4 v2 = *(const float4*)(xr2 + k);
    float4 v3 = *(const float4*)(xr3 + k);
    float w0 = Wl[(k + 0) * HID + lane];   // stride-1 across lanes
    float w1 = Wl[(k + 1) * HID + lane];
    float w2 = Wl[(k + 2) * HID + lane];
    float w3 = Wl[(k + 3) * HID + lane];
    a0 = fmaf(v0.x, w0, a0); a0 = fmaf(v0.y, w1, a0);
    a0 = fmaf(v0.z, w2, a0); a0 = fmaf(v0.w, w3, a0);
    a1 = fmaf(v1.x, w0, a1); a1 = fmaf(v1.y, w1, a1);
    a1 = fmaf(v1.z, w2, a1); a1 = fmaf(v1.w, w3, a1);
    a2 = fmaf(v2.x, w0, a2); a2 = fmaf(v2.y, w1, a2);
    a2 = fmaf(v2.z, w2, a2); a2 = fmaf(v2.w, w3, a2);
    a3 = fmaf(v3.x, w0, a3); a3 = fmaf(v3.y, w1, a3);
    a3 = fmaf(v3.z, w2, a3); a3 = fmaf(v3.w, w3, a3);
  }

  float asl = a_s[lane], adl = a_d[lane];
  h[(size_t)(row0 + 0) * HID + lane] = __float2half(a0);
  h[(size_t)(row0 + 1) * HID + lane] = __float2half(a1);
  h[(size_t)(row0 + 2) * HID + lane] = __float2half(a2);
  h[(size_t)(row0 + 3) * HID + lane] = __float2half(a3);
  float s0 = a0 * asl, d0 = a0 * adl;
  float s1 = a1 * asl, d1 = a1 * adl;
  float s2 = a2 * asl, d2 = a2 * adl;
  float s3 = a3 * asl, d3 = a3 * adl;
  for (int o = 32; o; o >>= 1) {
    s0 += __shfl_xor(s0, o); d0 += __shfl_xor(d0, o);
    s1 += __shfl_xor(s1, o); d1 += __shfl_xor(d1, o);
    s2 += __shfl_xor(s2, o); d2 += __shfl_xor(d2, o);
    s3 += __shfl_xor(s3, o); d3 += __shfl_xor(d3, o);
  }
  if (lane == 0) {
    sv_out[row0 + 0] = s0; dv_out[row0 + 0] = d0;
    sv_out[row0 + 1] = s1; dv_out[row0 + 1] = d1;
    sv_out[row0 + 2] = s2; dv_out[row0 + 2] = d2;
    sv_out[row0 + 3] = s3; dv_out[row0 + 3] = d3;
  }
}

// ---------------- per-node GAT aggregation core ----------------
// Softmax: lane=edge (alpha=0 for lane>=deg), all FP32 logits.
// Gather: DUAL-EDGE layout, __half2 per lane (4B -> half the traffic of
// R9's float2 at the same instruction count). Lanes 0-31 even-slot edge,
// 32-63 odd; features (2L, 2L+1) per lane; 128B/row contiguous.
__device__ __forceinline__ float2 gat_node(
    int node, const int* __restrict__ rowptr, const int* __restrict__ esrc,
    const float* __restrict__ s, const float* __restrict__ d,
    const __half* __restrict__ h, int lane, int half, int fl) {
  int start = rowptr[node], end = rowptr[node + 1];
  int deg = end - start;
  float dn = d[node];
  float2 acc = {0.f, 0.f};
  if (deg <= 64) {
    int j = start + (lane < deg ? lane : 0);
    int sj = esrc[j];                         // coalesced
    float e = lrelu(s[sj] + dn);
    float ev = (lane < deg) ? e : -INFINITY;
    float m = ev;
    for (int o = 32; o; o >>= 1) m = fmaxf(m, __shfl_xor(m, o));
    float w = (lane < deg) ? __expf(e - m) : 0.f;
    float wsum = w;
    for (int o = 32; o; o >>= 1) wsum += __shfl_xor(wsum, o);
    float alpha = w / wsum;                   // 0 for slots >= deg
    for (int t = 0; t < deg; t += 8) {
#pragma unroll
      for (int i = 0; i < 4; ++i) {
        int e0 = t + 2 * i;
        int p0 = __builtin_amdgcn_readlane(sj, e0);
        int p1 = __builtin_amdgcn_readlane(sj, e0 + 1);
        float a0 = readlane_f(alpha, e0);
        float a1 = readlane_f(alpha, e0 + 1);
        int ps = half ? p1 : p0;
        float aw = half ? a1 : a0;
        float2 hv = __half22float2(*(const __half2*)&h[(size_t)ps * HID + fl]);
        acc.x = fmaf(aw, hv.x, acc.x);
        acc.y = fmaf(aw, hv.y, acc.y);
      }
    }
  } else {
    float m = -INFINITY;
    for (int j = start + lane; j < end; j += 64)
      m = fmaxf(m, lrelu(s[esrc[j]] + dn));
    for (int o = 32; o; o >>= 1) m = fmaxf(m, __shfl_xor(m, o));
    float wsum = 0.f;
    for (int j = start + lane; j < end; j += 64)
      wsum += __expf(lrelu(s[esrc[j]] + dn) - m);
    for (int o = 32; o; o >>= 1) wsum += __shfl_xor(wsum, o);
    float inv = 1.0f / wsum;
    for (int cb = start; cb < end; cb += 64) {
      int cc = min(64, end - cb);
      int j = cb + (lane < cc ? lane : 0);
      int sj = esrc[j];
      float alpha = (lane < cc) ? __expf(lrelu(s[sj] + dn) - m) * inv : 0.f;
      for (int t = 0; t < cc; t += 8) {
#pragma unroll
        for (int i = 0; i < 4; ++i) {
          int e0 = t + 2 * i;
          int p0 = __builtin_amdgcn_readlane(sj, e0);
          int p1 = __builtin_amdgcn_readlane(sj, e0 + 1);
          float a0 = readlane_f(alpha, e0);
          float a1 = readlane_f(alpha, e0 + 1);
          int ps = half ? p1 : p0;
          float aw = half ? a1 : a0;
          float2 hv = __half22float2(*(const __half2*)&h[(size_t)ps * HID + fl]);
          acc.x = fmaf(aw, hv.x, acc.x);
          acc.y = fmaf(aw, hv.y, acc.y);
        }
      }
    }
  }
  acc.x += __shfl_xor(acc.x, 32);
  acc.y += __shfl_xor(acc.y, 32);
  return acc;
}

// layer-1 aggregation: strided nodes, writes y (fp32) + BN stats.
__global__ __launch_bounds__(256) void gat_agg_k(
    const int* __restrict__ rowptr, const int* __restrict__ esrc,
    const float* __restrict__ s, const float* __restrict__ d,
    const __half* __restrict__ h, const float* __restrict__ bias,
    float* __restrict__ y, float* __restrict__ fsum, float* __restrict__ fsq) {
  __shared__ float lsum[HID], lsq[HID];
  int tid = threadIdx.x;
  if (tid < HID) { lsum[tid] = 0.f; lsq[tid] = 0.f; }
  __syncthreads();
  int lane = tid & 63;
  int half = lane >> 5;
  int fl = (lane & 31) * 2;
  float2 bv = *(const float2*)&bias[fl];
  float2 ls = {0.f, 0.f}, lq = {0.f, 0.f};
  int wave = blockIdx.x * 4 + (tid >> 6);
  int nwaves = gridDim.x * 4;
  for (int node = wave; node < NN; node += nwaves) {
    float2 acc = gat_node(node, rowptr, esrc, s, d, h, lane, half, fl);
    float vx = fmaxf(acc.x + bv.x, 0.f);
    float vy = fmaxf(acc.y + bv.y, 0.f);
    if (half == 0) {
      *(float2*)&y[(size_t)node * HID + fl] = make_float2(vx, vy);
      ls.x += vx; ls.y += vy;
      lq.x += vx * vx; lq.y += vy * vy;
    }
  }
  if (lane < 32) {
    atomicAdd(&lsum[fl + 0], ls.x);
    atomicAdd(&lsum[fl + 1], ls.y);
    atomicAdd(&lsq[fl + 0], lq.x);
    atomicAdd(&lsq[fl + 1], lq.y);
  }
  __syncthreads();
  if (tid < HID) { atomicAdd(&fsum[tid], lsum[tid]); atomicAdd(&fsq[tid], lsq[tid]); }
}

// layer-2 aggregation + fused pooling: contiguous node ranges (batch is
// sorted) -> register-accumulate per graph run, one atomic flush per run.
__global__ __launch_bounds__(256) void gat_agg_pool_k(
    const int* __restrict__ rowptr, const int* __restrict__ esrc,
    const float* __restrict__ s, const float* __restrict__ d,
    const __half* __restrict__ h, const float* __restrict__ bias,
    const int* __restrict__ batch, float* __restrict__ pooled,
    float* __restrict__ cnt, float* __restrict__ fsum, float* __restrict__ fsq) {
  __shared__ float lsum[HID], lsq[HID];
  int tid = threadIdx.x;
  if (tid < HID) { lsum[tid] = 0.f; lsq[tid] = 0.f; }
  __syncthreads();
  int lane = tid & 63;
  int half = lane >> 5;
  int fl = (lane & 31) * 2;
  float2 bv = *(const float2*)&bias[fl];
  float2 ls = {0.f, 0.f}, lq = {0.f, 0.f};
  int wave = blockIdx.x * 4 + (tid >> 6);
  int nwaves = gridDim.x * 4;
  int per = (NN + nwaves - 1) / nwaves;
  int lo = wave * per, hi = min(lo + per, NN);
  if (lo < hi) {
    int g = batch[lo];
    float2 pacc = {0.f, 0.f};
    float c = 0.f;
    for (int node = lo; node < hi; ++node) {
      int bg = batch[node];                  // wave-uniform
      if (bg != g) {
        if (half == 0) {
          atomicAdd(&pooled[g * HID + fl + 0], pacc.x);
          atomicAdd(&pooled[g * HID + fl + 1], pacc.y);
        }
        if (lane == 0) atomicAdd(&cnt[g], c);
        g = bg; pacc.x = 0.f; pacc.y = 0.f; c = 0.f;
      }
      float2 acc = gat_node(node, rowptr, esrc, s, d, h, lane, half, fl);
      float vx = fmaxf(acc.x + bv.x, 0.f);
      float vy = fmaxf(acc.y + bv.y, 0.f);
      pacc.x += vx; pacc.y += vy; c += 1.f;
      if (half == 0) {
        ls.x += vx; ls.y += vy;
        lq.x += vx * vx; lq.y += vy * vy;
      }
    }
    if (half == 0) {
      atomicAdd(&pooled[g * HID + fl + 0], pacc.x);
      atomicAdd(&pooled[g * HID + fl + 1], pacc.y);
    }
    if (lane == 0) atomicAdd(&cnt[g], c);
  }
  if (lane < 32) {
    atomicAdd(&lsum[fl + 0], ls.x);
    atomicAdd(&lsum[fl + 1], ls.y);
    atomicAdd(&lsq[fl + 0], lq.x);
    atomicAdd(&lsq[fl + 1], lq.y);
  }
  __syncthreads();
  if (tid < HID) { atomicAdd(&fsum[tid], lsum[tid]); atomicAdd(&fsq[tid], lsq[tid]); }
}

// one block (64 threads) per graph: BN2 affine (inline from fsum2/fsq2)
// + mean + full MLP head.
__global__ __launch_bounds__(64) void mlp_head(
    const float* __restrict__ pooled, const float* __restrict__ cnt,
    const float* __restrict__ fsum, const float* __restrict__ fsq,
    const float* __restrict__ bng, const float* __restrict__ bnb,
    const float* __restrict__ m1w, const float* __restrict__ m1b,
    const float* __restrict__ m2w, const float* __restrict__ m2b,
    const float* __restrict__ m3w, const float* __restrict__ m3b,
    const float* __restrict__ m4w, const float* __restrict__ m4b,
    float* __restrict__ out) {
  __shared__ float p[64], z1[64], z2[16], z3[8];
  int g = blockIdx.x, f = threadIdx.x;
  float m = fsum[f] * (1.0f / NN);
  float v = fsq[f] * (1.0f / NN) - m * m;
  float a = bng[f] * rsqrtf(v + BN_EPS);
  float c = bnb[f] - m * a;
  float cv = fmaxf(cnt[g], 1.0f);
  p[f] = a * pooled[g * 64 + f] / cv + c;
  __syncthreads();
  float a1 = m1b[f];
  for (int k = 0; k < 64; ++k) a1 += p[k] * m1w[k * 64 + f];
  z1[f] = fmaxf(a1, 0.f);
  __syncthreads();
  if (f < 16) {
    float a2 = m2b[f];
    for (int k = 0; k < 64; ++k) a2 += z1[k] * m2w[k * 16 + f];
    z2[f] = fmaxf(a2, 0.f);
  }
  __syncthreads();
  if (f < 8) {
    float a3 = m3b[f];
    for (int k = 0; k < 16; ++k) a3 += z2[k] * m3w[k * 8 + f];
    z3[f] = fmaxf(a3, 0.f);
  }
  __syncthreads();
  if (f < 10) {
    float a4 = m4b[f];
    for (int k = 0; k < 8; ++k) a4 += z3[k] * m4w[k * 10 + f];
    out[g * 10 + f] = a4;
  }
}

extern "C" void kernel_launch(void* const* d_in, const int* in_sizes, int n_in,
                              void* d_out, int out_size, void* d_ws, size_t ws_size,
                              hipStream_t stream) {
  const float* x   = (const float*)d_in[0];
  const int*   ei  = (const int*)d_in[1];
  const int*   bat = (const int*)d_in[2];
  const float* W1  = (const float*)d_in[3];
  const float* as1 = (const float*)d_in[4];
  const float* ad1 = (const float*)d_in[5];
  const float* b1  = (const float*)d_in[6];
  const float* W2  = (const float*)d_in[7];
  const float* as2 = (const float*)d_in[8];
  const float* ad2 = (const float*)d_in[9];
  const float* b2  = (const float*)d_in[10];
  const float* bng = (const float*)d_in[11];
  const float* bnb = (const float*)d_in[12];
  const float* m1w = (const float*)d_in[13];
  const float* m1b = (const float*)d_in[14];
  const float* m2w = (const float*)d_in[15];
  const float* m2b = (const float*)d_in[16];
  const float* m3w = (const float*)d_in[17];
  const float* m3b = (const float*)d_in[18];
  const float* m4w = (const float*)d_in[19];
  const float* m4b = (const float*)d_in[20];
  float* out = (float*)d_out;

  float* ws = (float*)d_ws;
  size_t off = 0;
  __half* hbuf = (__half*)(ws + off); off += (size_t)NN * HID / 2;  // fp16 h
  float* ybuf = ws + off; off += (size_t)NN * HID;   // layer-1 output y (fp32)
  float* sbuf = ws + off; off += NN;                 // alpha_s
  float* dbuf = ws + off; off += NN;                 // alpha_d
  int* rowptr = (int*)(ws + off); off += NN + 1;
  int* esrc   = (int*)(ws + off); off += ET;         // CSR: src per dst-sorted edge
  int* bukcur = (int*)(ws + off); off += NBUK;
  int* bukbase = (int*)(ws + off); off += NBUK;
  float* fsum1 = ws + off; off += HID;
  float* fsq1  = ws + off; off += HID;
  float* fsum2 = ws + off; off += HID;
  float* fsq2  = ws + off; off += HID;
  float* pooled = ws + off; off += (size_t)NG * HID; // raw per-graph sums
  float* cnt  = ws + off; off += NG;
  // 16MB staging aliases ybuf (stage dead before agg1 first writes ybuf)
  int2* stage = (int2*)ybuf;

  dim3 b256(256);
  const int gemmGrid = NN / 16;                      // 6250, exact
  const int p1Grid = (ET + P1_CHUNK - 1) / P1_CHUNK; // 416
  const int aggGrid = 2048;

  // ---------- CSR build (shared by both layers) ----------
  init_k<<<(NG * HID + 255) / 256, b256, 0, stream>>>(bukcur, fsum1, fsq1,
                                                      fsum2, fsq2, pooled, cnt);
  part1_k<<<p1Grid, b256, 0, stream>>>(ei, bukcur, stage);
  bukscan_k<<<1, 512, 0, stream>>>(bukcur, bukbase, rowptr);
  part2_k<<<NBUK, b256, 0, stream>>>(stage, bukcur, bukbase, rowptr, esrc);

  // ---------- layer 1 ----------
  gemm_att<INF_, false><<<gemmGrid, b256, 0, stream>>>(
      x, nullptr, nullptr, nullptr, nullptr, W1, as1, ad1, hbuf, sbuf, dbuf);
  gat_agg_k<<<aggGrid, b256, 0, stream>>>(rowptr, esrc, sbuf, dbuf, hbuf, b1,
                                          ybuf, fsum1, fsq1);

  // ---------- layer 2 (BN1 inline in gemm; pooling fused into agg) ----------
  gemm_att<HID, true><<<gemmGrid, b256, 0, stream>>>(
      ybuf, fsum1, fsq1, bng, bnb, W2, as2, ad2, hbuf, sbuf, dbuf);
  gat_agg_pool_k<<<aggGrid, b256, 0, stream>>>(rowptr, esrc, sbuf, dbuf, hbuf,
                                               b2, bat, pooled, cnt, fsum2, fsq2);

  // ---------- MLP head (BN2 inline) ----------
  mlp_head<<<NG, 64, 0, stream>>>(pooled, cnt, fsum2, fsq2, bng, bnb,
                                  m1w, m1b, m2w, m2b, m3w, m3b, m4w, m4b, out);
}

// Round 16
// 375.105 us; speedup vs baseline: 1.5944x; 1.0313x over previous
//
#include <hip/hip_runtime.h>
#include <hip/hip_fp16.h>

// Problem constants (match reference)
#define NN   100000              // nodes
#define NE   1600000             // edges before self loops
#define ET   (NE + NN)           // edges incl. self loops
#define INF_ 128                 // input features
#define HID  64                  // hidden
#define NG   256                 // graphs
#define BN_EPS 1e-5f
#define NEG  0.2f

// bucket partition geometry (CSR fill)
#define BSPAN_LOG 8
#define BSPAN     (1 << BSPAN_LOG)                 // 256 dst nodes per bucket
#define NBUK      ((NN + BSPAN - 1) / BSPAN)       // 391
#define BUKCAP    5120                             // >= mu+12sigma of bucket load
#define P1_EPT    16
#define P1_CHUNK  (256 * P1_EPT)                   // 4096 edges per block

__device__ __forceinline__ float lrelu(float v) { return v > 0.f ? v : NEG * v; }

__device__ __forceinline__ float readlane_f(float v, int l) {
  return __int_as_float(__builtin_amdgcn_readlane(__float_as_int(v), l));
}

// ---------------- unified init ----------------
__global__ __launch_bounds__(256) void init_k(
    int* __restrict__ bukcur,
    float* __restrict__ fsum1, float* __restrict__ fsq1,
    float* __restrict__ fsum2, float* __restrict__ fsq2,
    float* __restrict__ pooled, float* __restrict__ cnt) {
  int i = blockIdx.x * 256 + threadIdx.x;
  if (i < NBUK) bukcur[i] = i * BUKCAP;
  if (i < HID) { fsum1[i] = 0.f; fsq1[i] = 0.f; fsum2[i] = 0.f; fsq2[i] = 0.f; }
  if (i < NG * HID) pooled[i] = 0.f;
  if (i < NG) cnt[i] = 0.f;
}

// ---------------- CSR build (edges sorted by dst) ----------------
__global__ __launch_bounds__(256) void part1_k(const int* __restrict__ ei,
                                               int* __restrict__ bukcur,
                                               int2* __restrict__ stage) {
  __shared__ int hist[NBUK];
  __shared__ int base[NBUK];
  int t = threadIdx.x;
  for (int b = t; b < NBUK; b += 256) hist[b] = 0;
  __syncthreads();
  int chunk = blockIdx.x * P1_CHUNK;
  int myb[P1_EPT], myr[P1_EPT], mys[P1_EPT], myd[P1_EPT];
#pragma unroll
  for (int it = 0; it < P1_EPT; ++it) {
    int i = chunk + it * 256 + t;
    bool v = i < ET;
    int src = 0, dst = 0;
    if (v) {
      src = i < NE ? ei[i] : i - NE;
      dst = i < NE ? ei[NE + i] : i - NE;
    }
    myb[it] = v ? (dst >> BSPAN_LOG) : -1;
    mys[it] = src;
    myd[it] = dst;
    myr[it] = v ? atomicAdd(&hist[dst >> BSPAN_LOG], 1) : 0;
  }
  __syncthreads();
  for (int b = t; b < NBUK; b += 256)
    base[b] = hist[b] ? atomicAdd(&bukcur[b], hist[b]) : 0;
  __syncthreads();
#pragma unroll
  for (int it = 0; it < P1_EPT; ++it)
    if (myb[it] >= 0)
      stage[base[myb[it]] + myr[it]] = make_int2(mys[it], myd[it]);
}

__global__ __launch_bounds__(512) void bukscan_k(const int* __restrict__ bukcur,
                                                 int* __restrict__ bukbase,
                                                 int* __restrict__ rowptr) {
  __shared__ int sh[512];
  int t = threadIdx.x;
  int c = (t < NBUK) ? (bukcur[t] - t * BUKCAP) : 0;
  sh[t] = c;
  __syncthreads();
  for (int off = 1; off < 512; off <<= 1) {
    int add = (t >= off) ? sh[t - off] : 0;
    __syncthreads();
    sh[t] += add;
    __syncthreads();
  }
  if (t < NBUK) bukbase[t] = sh[t] - c;
  if (t == 0) rowptr[NN] = ET;
}

__global__ __launch_bounds__(256) void part2_k(const int2* __restrict__ stage,
                                               const int* __restrict__ bukcur,
                                               const int* __restrict__ bukbase,
                                               int* __restrict__ rowptr,
                                               int* __restrict__ esrc) {
  __shared__ int lcnt[BSPAN];
  __shared__ int lscan[BSPAN];
  int b = blockIdx.x;
  int node0 = b << BSPAN_LOG;
  int t = threadIdx.x;
  lcnt[t] = 0;
  __syncthreads();
  int s = b * BUKCAP, e = bukcur[b];
  for (int i = s + t; i < e; i += 256)
    atomicAdd(&lcnt[stage[i].y - node0], 1);
  __syncthreads();
  int v = lcnt[t];
  lscan[t] = v;
  __syncthreads();
  for (int off = 1; off < 256; off <<= 1) {
    int add = (t >= off) ? lscan[t - off] : 0;
    __syncthreads();
    lscan[t] += add;
    __syncthreads();
  }
  int excl = bukbase[b] + lscan[t] - v;
  if (node0 + t < NN) rowptr[node0 + t] = excl;
  lcnt[t] = excl;
  __syncthreads();
  for (int i = s + t; i < e; i += 256) {
    int2 p = stage[i];
    int pos = atomicAdd(&lcnt[p.y - node0], 1);
    esrc[pos] = p.x;
  }
}

// ---------------- GEMM + attention logits (v4 + fp16 h) ----------------
template <int K, bool STATS>
__global__ __launch_bounds__(256) void gemm_att(
    const float* __restrict__ x,
    const float* __restrict__ fsum, const float* __restrict__ fsq,
    const float* __restrict__ bng, const float* __restrict__ bnb,
    const float* __restrict__ W,
    const float* __restrict__ a_s, const float* __restrict__ a_d,
    __half* __restrict__ h, float* __restrict__ sv_out, float* __restrict__ dv_out) {
  __shared__ float Wl[K * HID];          // [k][f]: lane reads stride-1
  __shared__ float cvec[HID];
  __shared__ float scl[HID], shf[HID];
  int tid = threadIdx.x;
  if (tid < HID) {
    cvec[tid] = 0.f;
    if (STATS) {
      float m = fsum[tid] * (1.0f / NN);
      float v = fsq[tid] * (1.0f / NN) - m * m;
      float a = bng[tid] * rsqrtf(v + BN_EPS);
      scl[tid] = a;
      shf[tid] = bnb[tid] - m * a;
    }
  }
  __syncthreads();
  if (STATS) {
    float clocal = 0.f;
    for (int i = tid; i < K * HID; i += 256) {
      int k = i >> 6;
      float w = W[i];
      clocal += shf[k] * w;
      Wl[i] = w * scl[k];
    }
    atomicAdd(&cvec[tid & 63], clocal);
  } else {
    for (int i = tid; i < K * HID; i += 256) Wl[i] = W[i];
  }
  __syncthreads();

  int lane = tid & 63;
  int wid = tid >> 6;
  int row0 = blockIdx.x * 16 + wid * 4;
  int ur = __builtin_amdgcn_readfirstlane(row0);
  const float* xr0 = x + (size_t)ur * K;   // uniform -> scalar loads
  const float* xr1 = xr0 + K;
  const float* xr2 = xr0 + 2 * K;
  const float* xr3 = xr0 + 3 * K;
  float cv = cvec[lane];
  float a0 = cv, a1 = cv, a2 = cv, a3 = cv;
#pragma unroll 4
  for (int k = 0; k < K; k += 4) {
    float4 v0 = *(const float4*)(xr0 + k);
    float4 v1 = *(const float4*)(xr1 + k);
    float4 v2 = *(const float4*)(xr2 + k);
    float4 v3 = *(const float4*)(xr3 + k);
    float w0 = Wl[(k + 0) * HID + lane];
    float w1 = Wl[(k + 1) * HID + lane];
    float w2 = Wl[(k + 2) * HID + lane];
    float w3 = Wl[(k + 3) * HID + lane];
    a0 = fmaf(v0.x, w0, a0); a0 = fmaf(v0.y, w1, a0);
    a0 = fmaf(v0.z, w2, a0); a0 = fmaf(v0.w, w3, a0);
    a1 = fmaf(v1.x, w0, a1); a1 = fmaf(v1.y, w1, a1);
    a1 = fmaf(v1.z, w2, a1); a1 = fmaf(v1.w, w3, a1);
    a2 = fmaf(v2.x, w0, a2); a2 = fmaf(v2.y, w1, a2);
    a2 = fmaf(v2.z, w2, a2); a2 = fmaf(v2.w, w3, a2);
    a3 = fmaf(v3.x, w0, a3); a3 = fmaf(v3.y, w1, a3);
    a3 = fmaf(v3.z, w2, a3); a3 = fmaf(v3.w, w3, a3);
  }

  float asl = a_s[lane], adl = a_d[lane];
  h[(size_t)(row0 + 0) * HID + lane] = __float2half(a0);
  h[(size_t)(row0 + 1) * HID + lane] = __float2half(a1);
  h[(size_t)(row0 + 2) * HID + lane] = __float2half(a2);
  h[(size_t)(row0 + 3) * HID + lane] = __float2half(a3);
  float s0 = a0 * asl, d0 = a0 * adl;
  float s1 = a1 * asl, d1 = a1 * adl;
  float s2 = a2 * asl, d2 = a2 * adl;
  float s3 = a3 * asl, d3 = a3 * adl;
  for (int o = 32; o; o >>= 1) {
    s0 += __shfl_xor(s0, o); d0 += __shfl_xor(d0, o);
    s1 += __shfl_xor(s1, o); d1 += __shfl_xor(d1, o);
    s2 += __shfl_xor(s2, o); d2 += __shfl_xor(d2, o);
    s3 += __shfl_xor(s3, o); d3 += __shfl_xor(d3, o);
  }
  if (lane == 0) {
    sv_out[row0 + 0] = s0; dv_out[row0 + 0] = d0;
    sv_out[row0 + 1] = s1; dv_out[row0 + 1] = d1;
    sv_out[row0 + 2] = s2; dv_out[row0 + 2] = d2;
    sv_out[row0 + 3] = s3; dv_out[row0 + 3] = d3;
  }
}

// ---------------- half-wave node processing (deg <= 32) ----------------
// 32 lanes own one node: softmax at width 32 (xor 16..1 stays in half),
// gather 1 row per half per instruction (half2 -> 64 features), 4-deep.
// acc covers features fl = (lane&31)*2. R15: agg was invariant to traffic
// (fp16 halved FETCH, dur unchanged) -> latency-chain bound; two nodes
// per wave doubles chains in flight and halves softmax work per node.
__device__ __forceinline__ float2 gat_node_half(
    int node, int start, int deg, const int* __restrict__ esrc,
    const float* __restrict__ s, const float* __restrict__ d,
    const __half* __restrict__ h, int lane32, int base, int fl) {
  float dn = d[node];
  int j = start + (lane32 < deg ? lane32 : 0);
  int sj = esrc[j];
  float e = lrelu(s[sj] + dn);
  float ev = (lane32 < deg) ? e : -INFINITY;
  float m = ev;
  for (int o = 16; o; o >>= 1) m = fmaxf(m, __shfl_xor(m, o));
  float w = (lane32 < deg) ? __expf(e - m) : 0.f;
  float wsum = w;
  for (int o = 16; o; o >>= 1) wsum += __shfl_xor(wsum, o);
  float alpha = w / wsum;                 // 0 for slots >= deg
  float2 acc = {0.f, 0.f};
  for (int t = 0; t < deg; t += 4) {
#pragma unroll
    for (int i = 0; i < 4; ++i) {
      int p = __shfl(sj, base + t + i);
      float a = __shfl(alpha, base + t + i);
      unsigned off = ((unsigned)p << 6) + fl;     // 32-bit addressing
      float2 hv = __half22float2(*(const __half2*)&h[off]);
      acc.x = fmaf(a, hv.x, acc.x);
      acc.y = fmaf(a, hv.y, acc.y);
    }
  }
  return acc;
}

// full-wave fallback (deg > 32): R9 dual-edge layout; returns full sums.
__device__ float2 gat_node_full(
    int node, const int* __restrict__ rowptr, const int* __restrict__ esrc,
    const float* __restrict__ s, const float* __restrict__ d,
    const __half* __restrict__ h, int lane, int half, int fl) {
  int start = rowptr[node], end = rowptr[node + 1];
  int deg = end - start;
  float dn = d[node];
  float2 acc = {0.f, 0.f};
  if (deg <= 64) {
    int j = start + (lane < deg ? lane : 0);
    int sj = esrc[j];
    float e = lrelu(s[sj] + dn);
    float ev = (lane < deg) ? e : -INFINITY;
    float m = ev;
    for (int o = 32; o; o >>= 1) m = fmaxf(m, __shfl_xor(m, o));
    float w = (lane < deg) ? __expf(e - m) : 0.f;
    float wsum = w;
    for (int o = 32; o; o >>= 1) wsum += __shfl_xor(wsum, o);
    float alpha = w / wsum;
    for (int t = 0; t < deg; t += 8) {
#pragma unroll
      for (int i = 0; i < 4; ++i) {
        int e0 = t + 2 * i;
        int p0 = __builtin_amdgcn_readlane(sj, e0);
        int p1 = __builtin_amdgcn_readlane(sj, e0 + 1);
        float a0 = readlane_f(alpha, e0);
        float a1 = readlane_f(alpha, e0 + 1);
        int ps = half ? p1 : p0;
        float aw = half ? a1 : a0;
        unsigned off = ((unsigned)ps << 6) + fl;
        float2 hv = __half22float2(*(const __half2*)&h[off]);
        acc.x = fmaf(aw, hv.x, acc.x);
        acc.y = fmaf(aw, hv.y, acc.y);
      }
    }
  } else {
    float m = -INFINITY;
    for (int j = start + lane; j < end; j += 64)
      m = fmaxf(m, lrelu(s[esrc[j]] + dn));
    for (int o = 32; o; o >>= 1) m = fmaxf(m, __shfl_xor(m, o));
    float wsum = 0.f;
    for (int j = start + lane; j < end; j += 64)
      wsum += __expf(lrelu(s[esrc[j]] + dn) - m);
    for (int o = 32; o; o >>= 1) wsum += __shfl_xor(wsum, o);
    float inv = 1.0f / wsum;
    for (int cb = start; cb < end; cb += 64) {
      int cc = min(64, end - cb);
      int j = cb + (lane < cc ? lane : 0);
      int sj = esrc[j];
      float alpha = (lane < cc) ? __expf(lrelu(s[sj] + dn) - m) * inv : 0.f;
      for (int t = 0; t < cc; t += 8) {
#pragma unroll
        for (int i = 0; i < 4; ++i) {
          int e0 = t + 2 * i;
          int p0 = __builtin_amdgcn_readlane(sj, e0);
          int p1 = __builtin_amdgcn_readlane(sj, e0 + 1);
          float a0 = readlane_f(alpha, e0);
          float a1 = readlane_f(alpha, e0 + 1);
          int ps = half ? p1 : p0;
          float aw = half ? a1 : a0;
          unsigned off = ((unsigned)ps << 6) + fl;
          float2 hv = __half22float2(*(const __half2*)&h[off]);
          acc.x = fmaf(aw, hv.x, acc.x);
          acc.y = fmaf(aw, hv.y, acc.y);
        }
      }
    }
  }
  acc.x += __shfl_xor(acc.x, 32);
  acc.y += __shfl_xor(acc.y, 32);
  return acc;
}

// pair dispatcher: lanes 0-31 end with node nA's features, 32-63 with nB's.
__device__ __forceinline__ float2 gat_pair(
    int nA, const int* __restrict__ rowptr, const int* __restrict__ esrc,
    const float* __restrict__ s, const float* __restrict__ d,
    const __half* __restrict__ h, int lane, int half, int lane32, int fl) {
  int nB = nA + 1;
  int sA = rowptr[nA], sB = rowptr[nB], eB = rowptr[nB + 1];
  int degA = sB - sA, degB = eB - sB;
  if (degA <= 32 && degB <= 32) {
    int node = half ? nB : nA;
    int start = half ? sB : sA;
    int deg = half ? degB : degA;
    return gat_node_half(node, start, deg, esrc, s, d, h, lane32, half << 5, fl);
  }
  float2 aA = gat_node_full(nA, rowptr, esrc, s, d, h, lane, half, fl);
  float2 aB = gat_node_full(nB, rowptr, esrc, s, d, h, lane, half, fl);
  return half ? aB : aA;
}

// layer-1 aggregation: strided node PAIRS; each half writes its node's y.
__global__ __launch_bounds__(256) void gat_agg_k(
    const int* __restrict__ rowptr, const int* __restrict__ esrc,
    const float* __restrict__ s, const float* __restrict__ d,
    const __half* __restrict__ h, const float* __restrict__ bias,
    float* __restrict__ y, float* __restrict__ fsum, float* __restrict__ fsq) {
  __shared__ float lsum[HID], lsq[HID];
  int tid = threadIdx.x;
  if (tid < HID) { lsum[tid] = 0.f; lsq[tid] = 0.f; }
  __syncthreads();
  int lane = tid & 63;
  int half = lane >> 5;
  int lane32 = lane & 31;
  int fl = lane32 * 2;
  float2 bv = *(const float2*)&bias[fl];
  float2 ls = {0.f, 0.f}, lq = {0.f, 0.f};
  int wave = blockIdx.x * 4 + (tid >> 6);
  int nwaves = gridDim.x * 4;
  for (int p = wave; p < NN / 2; p += nwaves) {       // NN even
    int nA = 2 * p;
    float2 acc = gat_pair(nA, rowptr, esrc, s, d, h, lane, half, lane32, fl);
    float vx = fmaxf(acc.x + bv.x, 0.f);
    float vy = fmaxf(acc.y + bv.y, 0.f);
    int node = nA + half;
    *(float2*)&y[(size_t)node * HID + fl] = make_float2(vx, vy);
    ls.x += vx; ls.y += vy;
    lq.x += vx * vx; lq.y += vy * vy;
  }
  atomicAdd(&lsum[fl + 0], ls.x);
  atomicAdd(&lsum[fl + 1], ls.y);
  atomicAdd(&lsq[fl + 0], lq.x);
  atomicAdd(&lsq[fl + 1], lq.y);
  __syncthreads();
  if (tid < HID) { atomicAdd(&fsum[tid], lsum[tid]); atomicAdd(&fsq[tid], lsq[tid]); }
}

// layer-2 aggregation + fused pooling: contiguous EVEN-sized node ranges;
// per-half graph-run accumulation (halves flush independently).
__global__ __launch_bounds__(256) void gat_agg_pool_k(
    const int* __restrict__ rowptr, const int* __restrict__ esrc,
    const float* __restrict__ s, const float* __restrict__ d,
    const __half* __restrict__ h, const float* __restrict__ bias,
    const int* __restrict__ batch, float* __restrict__ pooled,
    float* __restrict__ cnt, float* __restrict__ fsum, float* __restrict__ fsq) {
  __shared__ float lsum[HID], lsq[HID];
  int tid = threadIdx.x;
  if (tid < HID) { lsum[tid] = 0.f; lsq[tid] = 0.f; }
  __syncthreads();
  int lane = tid & 63;
  int half = lane >> 5;
  int lane32 = lane & 31;
  int fl = lane32 * 2;
  float2 bv = *(const float2*)&bias[fl];
  float2 ls = {0.f, 0.f}, lq = {0.f, 0.f};
  int wave = blockIdx.x * 4 + (tid >> 6);
  int nwaves = gridDim.x * 4;
  int per = (((NN / 2) + nwaves - 1) / nwaves) * 2;   // even range size
  int lo = wave * per, hi = min(lo + per, NN);        // hi even (NN even)
  if (lo < hi) {
    int g = batch[lo + half];
    float2 pacc = {0.f, 0.f};
    float c = 0.f;
    for (int nA = lo; nA < hi; nA += 2) {
      int myn = nA + half;
      int bg = batch[myn];                   // uniform within half
      if (bg != g) {
        atomicAdd(&pooled[g * HID + fl + 0], pacc.x);
        atomicAdd(&pooled[g * HID + fl + 1], pacc.y);
        if (lane32 == 0) atomicAdd(&cnt[g], c);
        g = bg; pacc.x = 0.f; pacc.y = 0.f; c = 0.f;
      }
      float2 acc = gat_pair(nA, rowptr, esrc, s, d, h, lane, half, lane32, fl);
      float vx = fmaxf(acc.x + bv.x, 0.f);
      float vy = fmaxf(acc.y + bv.y, 0.f);
      pacc.x += vx; pacc.y += vy; c += 1.f;
      ls.x += vx; ls.y += vy;
      lq.x += vx * vx; lq.y += vy * vy;
    }
    atomicAdd(&pooled[g * HID + fl + 0], pacc.x);
    atomicAdd(&pooled[g * HID + fl + 1], pacc.y);
    if (lane32 == 0) atomicAdd(&cnt[g], c);
  }
  atomicAdd(&lsum[fl + 0], ls.x);
  atomicAdd(&lsum[fl + 1], ls.y);
  atomicAdd(&lsq[fl + 0], lq.x);
  atomicAdd(&lsq[fl + 1], lq.y);
  __syncthreads();
  if (tid < HID) { atomicAdd(&fsum[tid], lsum[tid]); atomicAdd(&fsq[tid], lsq[tid]); }
}

// one block (64 threads) per graph: BN2 affine + mean + full MLP head
__global__ __launch_bounds__(64) void mlp_head(
    const float* __restrict__ pooled, const float* __restrict__ cnt,
    const float* __restrict__ fsum, const float* __restrict__ fsq,
    const float* __restrict__ bng, const float* __restrict__ bnb,
    const float* __restrict__ m1w, const float* __restrict__ m1b,
    const float* __restrict__ m2w, const float* __restrict__ m2b,
    const float* __restrict__ m3w, const float* __restrict__ m3b,
    const float* __restrict__ m4w, const float* __restrict__ m4b,
    float* __restrict__ out) {
  __shared__ float p[64], z1[64], z2[16], z3[8];
  int g = blockIdx.x, f = threadIdx.x;
  float m = fsum[f] * (1.0f / NN);
  float v = fsq[f] * (1.0f / NN) - m * m;
  float a = bng[f] * rsqrtf(v + BN_EPS);
  float c = bnb[f] - m * a;
  float cv = fmaxf(cnt[g], 1.0f);
  p[f] = a * pooled[g * 64 + f] / cv + c;
  __syncthreads();
  float a1 = m1b[f];
  for (int k = 0; k < 64; ++k) a1 += p[k] * m1w[k * 64 + f];
  z1[f] = fmaxf(a1, 0.f);
  __syncthreads();
  if (f < 16) {
    float a2 = m2b[f];
    for (int k = 0; k < 64; ++k) a2 += z1[k] * m2w[k * 16 + f];
    z2[f] = fmaxf(a2, 0.f);
  }
  __syncthreads();
  if (f < 8) {
    float a3 = m3b[f];
    for (int k = 0; k < 16; ++k) a3 += z2[k] * m3w[k * 8 + f];
    z3[f] = fmaxf(a3, 0.f);
  }
  __syncthreads();
  if (f < 10) {
    float a4 = m4b[f];
    for (int k = 0; k < 8; ++k) a4 += z3[k] * m4w[k * 10 + f];
    out[g * 10 + f] = a4;
  }
}

extern "C" void kernel_launch(void* const* d_in, const int* in_sizes, int n_in,
                              void* d_out, int out_size, void* d_ws, size_t ws_size,
                              hipStream_t stream) {
  const float* x   = (const float*)d_in[0];
  const int*   ei  = (const int*)d_in[1];
  const int*   bat = (const int*)d_in[2];
  const float* W1  = (const float*)d_in[3];
  const float* as1 = (const float*)d_in[4];
  const float* ad1 = (const float*)d_in[5];
  const float* b1  = (const float*)d_in[6];
  const float* W2  = (const float*)d_in[7];
  const float* as2 = (const float*)d_in[8];
  const float* ad2 = (const float*)d_in[9];
  const float* b2  = (const float*)d_in[10];
  const float* bng = (const float*)d_in[11];
  const float* bnb = (const float*)d_in[12];
  const float* m1w = (const float*)d_in[13];
  const float* m1b = (const float*)d_in[14];
  const float* m2w = (const float*)d_in[15];
  const float* m2b = (const float*)d_in[16];
  const float* m3w = (const float*)d_in[17];
  const float* m3b = (const float*)d_in[18];
  const float* m4w = (const float*)d_in[19];
  const float* m4b = (const float*)d_in[20];
  float* out = (float*)d_out;

  float* ws = (float*)d_ws;
  size_t off = 0;
  __half* hbuf = (__half*)(ws + off); off += (size_t)NN * HID / 2;  // fp16 h
  float* ybuf = ws + off; off += (size_t)NN * HID;   // layer-1 output y (fp32)
  float* sbuf = ws + off; off += NN;                 // alpha_s
  float* dbuf = ws + off; off += NN;                 // alpha_d
  int* rowptr = (int*)(ws + off); off += NN + 1;
  int* esrc   = (int*)(ws + off); off += ET;         // CSR: src per dst-sorted edge
  int* bukcur = (int*)(ws + off); off += NBUK;
  int* bukbase = (int*)(ws + off); off += NBUK;
  float* fsum1 = ws + off; off += HID;
  float* fsq1  = ws + off; off += HID;
  float* fsum2 = ws + off; off += HID;
  float* fsq2  = ws + off; off += HID;
  float* pooled = ws + off; off += (size_t)NG * HID; // raw per-graph sums
  float* cnt  = ws + off; off += NG;
  // 16MB staging aliases ybuf (stage dead before agg1 first writes ybuf)
  int2* stage = (int2*)ybuf;

  dim3 b256(256);
  const int gemmGrid = NN / 16;                      // 6250, exact
  const int p1Grid = (ET + P1_CHUNK - 1) / P1_CHUNK; // 416
  const int aggGrid = 2048;

  // ---------- CSR build (shared by both layers) ----------
  init_k<<<(NG * HID + 255) / 256, b256, 0, stream>>>(bukcur, fsum1, fsq1,
                                                      fsum2, fsq2, pooled, cnt);
  part1_k<<<p1Grid, b256, 0, stream>>>(ei, bukcur, stage);
  bukscan_k<<<1, 512, 0, stream>>>(bukcur, bukbase, rowptr);
  part2_k<<<NBUK, b256, 0, stream>>>(stage, bukcur, bukbase, rowptr, esrc);

  // ---------- layer 1 ----------
  gemm_att<INF_, false><<<gemmGrid, b256, 0, stream>>>(
      x, nullptr, nullptr, nullptr, nullptr, W1, as1, ad1, hbuf, sbuf, dbuf);
  gat_agg_k<<<aggGrid, b256, 0, stream>>>(rowptr, esrc, sbuf, dbuf, hbuf, b1,
                                          ybuf, fsum1, fsq1);

  // ---------- layer 2 (BN1 inline in gemm; pooling fused into agg) ----------
  gemm_att<HID, true><<<gemmGrid, b256, 0, stream>>>(
      ybuf, fsum1, fsq1, bng, bnb, W2, as2, ad2, hbuf, sbuf, dbuf);
  gat_agg_pool_k<<<aggGrid, b256, 0, stream>>>(rowptr, esrc, sbuf, dbuf, hbuf,
                                               b2, bat, pooled, cnt, fsum2, fsq2);

  // ---------- MLP head (BN2 inline) ----------
  mlp_head<<<NG, 64, 0, stream>>>(pooled, cnt, fsum2, fsq2, bng, bnb,
                                  m1w, m1b, m2w, m2b, m3w, m3b, m4w, m4b, out);
}